// Round 1
// baseline (924.725 us; speedup 1.0000x reference)
//
#include <hip/hip_runtime.h>
#include <hip/hip_bf16.h>

// ---------------------------------------------------------------------------
// TokenDiscrepancyLoss: loss = 0.1 * sum_{mask} [ (||t||^2 + sum_c p_c (||c||^2 - 2 t.c)) / H ]
// with p = softmax(hs @ W + b) over C=8192.
//
// R7: k_dual ported to MX-scaled fp8 MFMA (v_mfma_scale_f32_32x32x64_f8f6f4,
// unit e8m0 scales -> exact pow2, ~2.3x FLOP rate vs non-scaled fp8).
// kc-chunk layout changed to [half2][b4 2][c128][16B] so each 32B/lane
// operand is two conflict-free stride-16B ds_read_b128. Phase-2 W scale
// (x16) absorbed into scale_b = 123 (2^-4). k_merge re-parallelized:
// 128 blocks x (64 tok x 4 strip-quarters) + LDS softmax-partial merge.
// Dispatches: memset, prep1, prep_a, k_dual, k_merge (5 total).
// ---------------------------------------------------------------------------

#define H        1024
#define CBN      8192
#define NTOK     8192
#define MT       128
#define NTILE    128
#define BK       64
#define NKC      16               // H / BK
#define NCHK     128              // partial strips (one per 64-col wave tile)
#define LOSSW    0.1f
#define CTC      1024.0f          // centering for bf16 ct registers
#define WSCALE   16.0f            // W pre-scale (pow2) for fp8 range
#define SB_UNIT  127              // e8m0 scale = 2^0
#define SB_W     123              // e8m0 scale = 2^-4 (undoes WSCALE)
#define SLAB     131072           // bytes per 128-row panel: 16kc*8KB

typedef __attribute__((ext_vector_type(4)))  int   i32x4;
typedef __attribute__((ext_vector_type(8)))  int   i32x8;
typedef __attribute__((ext_vector_type(16))) float f32x16;

__device__ __forceinline__ unsigned short f2bf(float f) {
  union { float f; unsigned u; } x; x.f = f;
  return (unsigned short)((x.u + 0x7FFFu + ((x.u >> 16) & 1u)) >> 16); // RNE
}
__device__ __forceinline__ float bf2f(unsigned short u) {
  union { unsigned u; float f; } x; x.u = (unsigned)u << 16;
  return x.f;
}

// ---- fp32 -> fp8 e4m3fn (OCP) ----
__device__ unsigned char f2fp8_sw(float f) {
  float a = fabsf(f);
  unsigned s = f < 0.f ? 0x80u : 0u;
  if (!(a < 448.f)) return (unsigned char)(s | 0x7Eu);
  if (a < 0.0009765625f) return (unsigned char)s;
  int e; float m = frexpf(a, &e);
  int te = e - 1;
  if (te < -6) {
    int q = (int)rintf(a * 512.f); if (q > 7) q = 7;
    return (unsigned char)(s | q);
  }
  int q = (int)rintf((2.f * m - 1.f) * 8.f);
  int E = te + 7, M = q;
  if (q == 8) { E += 1; M = 0; }
  if (E > 15) return (unsigned char)(s | 0x7Eu);
  return (unsigned char)(s | (E << 3) | M);
}
__device__ __forceinline__ unsigned pack4(float a, float b, float c, float d) {
#if __has_builtin(__builtin_amdgcn_cvt_pk_fp8_f32)
  int r = __builtin_amdgcn_cvt_pk_fp8_f32(a, b, 0, false);
  r     = __builtin_amdgcn_cvt_pk_fp8_f32(c, d, r, true);
  return (unsigned)r;
#else
  return (unsigned)f2fp8_sw(a) | ((unsigned)f2fp8_sw(b) << 8) |
         ((unsigned)f2fp8_sw(c) << 16) | ((unsigned)f2fp8_sw(d) << 24);
#endif
}

// kc-chunk internal offset for (row c, local k octet g in [0,8)):
//   half = g>>2 (k>>5), b4 = (g>>1)&1 ((k>>4)&1), lo8 = (g&1)*8 (k&8)
//   off  = half*4096 + b4*2048 + c*16 + lo8
__device__ __forceinline__ int slab_off(int g, int c) {
  return ((g >> 2) << 12) + (((g >> 1) & 1) << 11) + (c << 4) + ((g & 1) << 3);
}

// async global->LDS DMA, 16B/lane; LDS dest = wave-uniform base + lane*16
__device__ __forceinline__ void load_lds16(const void* g, void* l) {
  __builtin_amdgcn_global_load_lds((const __attribute__((address_space(1))) void*)g,
                                   (__attribute__((address_space(3))) void*)l,
                                   16, 0, 0);
}
__device__ __forceinline__ void wait_vm4() { asm volatile("s_waitcnt vmcnt(4)" ::: "memory"); }
__device__ __forceinline__ void wait_vm0() { asm volatile("s_waitcnt vmcnt(0)" ::: "memory"); }
__device__ __forceinline__ void barrier_raw() { asm volatile("s_barrier" ::: "memory"); }

// XCD-aware tile mapping
__device__ __forceinline__ void tile_map(int* tilex, int* tiley) {
  const int flat = blockIdx.y * 64 + blockIdx.x;
  const int xcd = flat & 7, loc = flat >> 3;
  *tiley = xcd * 8 + (loc & 7);
  *tilex = loc >> 3;
}

// ---------------- prep1: compact (32 blk) + W (1024 blk) + cb (256 blk) ----
__global__ __launch_bounds__(256) void k_prep1(
    const int* __restrict__ ids, const float* __restrict__ cb,
    const float* __restrict__ W,
    int* __restrict__ list, int* __restrict__ counter,
    float* __restrict__ csq,
    unsigned char* __restrict__ Wtb, unsigned char* __restrict__ Cbb) {
  __shared__ __align__(16) unsigned char tile[8192];
  const int b = blockIdx.x, t = threadIdx.x;
  if (b < 32) {
    int f = 0;
    #pragma unroll
    for (int j = 0; j < 16; ++j) f |= ids[2 * (t * 16 + j) + 1];
    int anyodd = __syncthreads_or(f);
    int i = b * 256 + t;
    int v = anyodd ? ids[i] : ids[2 * i];
    bool act = (v == 1);
    unsigned long long mask = __ballot(act);
    int lane = t & 63;
    int base = 0;
    if (lane == 0) base = atomicAdd(counter, __popcll(mask));
    base = __shfl(base, 0);
    if (act) list[base + __popcll(mask & ((1ull << lane) - 1ull))] = i;
  } else if (b < 1056) {
    // W [H][C] fp32 -> fp8 slab [tiley][kc][half][b4][c][16], scaled x16
    const int q = b - 32, tiley = q >> 4, kc = q & 15;
    const int c = t & 127, gh = t >> 7;
    unsigned char* dst = Wtb + (size_t)tiley * SLAB + (size_t)kc * 8192;
    #pragma unroll
    for (int gi = 0; gi < 4; ++gi) {
      const int g = gh * 4 + gi;
      const float* wp = W + (size_t)(kc * 64 + g * 8) * CBN + tiley * 128 + c;
      float v[8];
      #pragma unroll
      for (int j = 0; j < 8; ++j) v[j] = wp[(size_t)j * CBN] * WSCALE;
      uint2 pk;
      pk.x = pack4(v[0], v[1], v[2], v[3]);
      pk.y = pack4(v[4], v[5], v[6], v[7]);
      *(uint2*)(dst + slab_off(g, c)) = pk;
    }
  } else {
    // codebook [C][H] fp32 -> fp8 slab + csq partials
    const int q = b - 1056, tiley = q >> 2, kcg = q & 3;
    const int r = t >> 1, h = t & 1;
    const int c = tiley * 128 + r;
    float ss = 0.f;
    for (int kk = 0; kk < 4; ++kk) {
      const int kc = kcg * 4 + kk;
      const float4* s4 = (const float4*)(cb + (size_t)c * H + kc * 64 + h * 32);
      #pragma unroll
      for (int i = 0; i < 4; ++i) {
        float4 va = s4[2 * i], vb = s4[2 * i + 1];
        ss += va.x * va.x + va.y * va.y + va.z * va.z + va.w * va.w;
        ss += vb.x * vb.x + vb.y * vb.y + vb.z * vb.z + vb.w * vb.w;
        uint2 pk;
        pk.x = pack4(va.x, va.y, va.z, va.w);
        pk.y = pack4(vb.x, vb.y, vb.z, vb.w);
        *(uint2*)&tile[slab_off(h * 4 + i, r)] = pk;
      }
      __syncthreads();
      const uint4* tp = (const uint4*)tile;
      uint4 x0 = tp[t * 2], x1 = tp[t * 2 + 1];
      unsigned char* dst = Cbb + (size_t)tiley * SLAB + (size_t)kc * 8192 + t * 32;
      *(uint4*)dst = x0; *(uint4*)(dst + 16) = x1;
      __syncthreads();
    }
    ss += __shfl_xor(ss, 1);
    if (h == 0) atomicAdd(&csq[c], ss);
  }
}

// ------- gather active tokens -> fp8 slabs (hs, tg) + fp32 ||t||^2 ---------
__global__ __launch_bounds__(256) void k_prep_a(
    const float* __restrict__ hs, const float* __restrict__ tg,
    const int* __restrict__ list, const int* __restrict__ counter,
    unsigned char* __restrict__ Ahs, unsigned char* __restrict__ Atg,
    float* __restrict__ tsq) {
  const int n = *counter;
  const int n_pad = (n + MT - 1) & ~(MT - 1);
  const int tilex = blockIdx.x >> 2, kcg = blockIdx.x & 3;
  if (tilex * MT >= n_pad) return;
  __shared__ int stok[128];
  __shared__ __align__(16) unsigned char tile[8192];
  const int t = threadIdx.x, r = t >> 1, h = t & 1;
  if (t < 128) {
    int ga = tilex * MT + t;
    stok[t] = list[(ga < n) ? ga : 0];
  }
  __syncthreads();
  const size_t srow = (size_t)stok[r] * H;
  float ss = 0.f;
  for (int kk = 0; kk < 4; ++kk) {
    const int kc = kcg * 4 + kk;
    {
      const float4* s4 = (const float4*)(hs + srow + kc * 64 + h * 32);
      #pragma unroll
      for (int i = 0; i < 4; ++i) {
        float4 va = s4[2 * i], vb = s4[2 * i + 1];
        uint2 pk;
        pk.x = pack4(va.x, va.y, va.z, va.w);
        pk.y = pack4(vb.x, vb.y, vb.z, vb.w);
        *(uint2*)&tile[slab_off(h * 4 + i, r)] = pk;
      }
      __syncthreads();
      const uint4* tp = (const uint4*)tile;
      uint4 x0 = tp[t * 2], x1 = tp[t * 2 + 1];
      unsigned char* dst = Ahs + (size_t)tilex * SLAB + (size_t)kc * 8192 + t * 32;
      *(uint4*)dst = x0; *(uint4*)(dst + 16) = x1;
      __syncthreads();
    }
    {
      const float4* s4 = (const float4*)(tg + srow + kc * 64 + h * 32);
      #pragma unroll
      for (int i = 0; i < 4; ++i) {
        float4 va = s4[2 * i], vb = s4[2 * i + 1];
        ss += va.x * va.x + va.y * va.y + va.z * va.z + va.w * va.w;
        ss += vb.x * vb.x + vb.y * vb.y + vb.z * vb.z + vb.w * vb.w;
        uint2 pk;
        pk.x = pack4(va.x, va.y, va.z, va.w);
        pk.y = pack4(vb.x, vb.y, vb.z, vb.w);
        *(uint2*)&tile[slab_off(h * 4 + i, r)] = pk;
      }
      __syncthreads();
      const uint4* tp = (const uint4*)tile;
      uint4 x0 = tp[t * 2], x1 = tp[t * 2 + 1];
      unsigned char* dst = Atg + (size_t)tilex * SLAB + (size_t)kc * 8192 + t * 32;
      *(uint4*)dst = x0; *(uint4*)(dst + 16) = x1;
      __syncthreads();
    }
  }
  ss += __shfl_xor(ss, 1);
  if (h == 0) atomicAdd(&tsq[tilex * MT + r], ss);
}

// per-wave DMA batch: 4 contiguous 1 KB wave-loads (2 A granule-rows + 2 B)
#define ISSUE(Aslab, Bslab, kc, pb)                                        \
  do {                                                                     \
    const unsigned char* ap_ = (Aslab) + Aoff + (size_t)(kc) * 8192 + lane * 16; \
    const unsigned char* bp_ = (Bslab) + Boff + (size_t)(kc) * 8192 + lane * 16; \
    load_lds16(ap_ + w * 1024,       &sA[pb][w * 1024]);                   \
    load_lds16(ap_ + (w + 4) * 1024, &sA[pb][(w + 4) * 1024]);             \
    load_lds16(bp_ + w * 1024,       &sB[pb][w * 1024]);                   \
    load_lds16(bp_ + (w + 4) * 1024, &sB[pb][(w + 4) * 1024]);             \
  } while (0)

// one kc compute step: 4 MX-scaled 32x32x64 fp8 MFMA from buffer `cur`.
// Per-lane operand: 32 contiguous k-bytes = one MX block:
//   row = lane&31, k = (lane>>5)*32 + [0..31]
// -> two conflict-free stride-16B ds_read_b128 (b4=0 at +0, b4=1 at +2048).
#define COMPUTE_KC(cur, SB)                                                 \
  do {                                                                      \
    const unsigned char* abase = &sA[cur][rb];                              \
    const unsigned char* bbase = &sB[cur][rb];                              \
    i32x8 aF[2], bF[2];                                                     \
    _Pragma("unroll")                                                       \
    for (int mi = 0; mi < 2; ++mi) {                                        \
      i32x4 lo = *(const i32x4*)(abase + ((wr * 64 + mi * 32) << 4));       \
      i32x4 hh = *(const i32x4*)(abase + ((wr * 64 + mi * 32) << 4) + 2048);\
      aF[mi] = __builtin_shufflevector(lo, hh, 0, 1, 2, 3, 4, 5, 6, 7);     \
    }                                                                       \
    _Pragma("unroll")                                                       \
    for (int ni = 0; ni < 2; ++ni) {                                        \
      i32x4 lo = *(const i32x4*)(bbase + ((wc * 64 + ni * 32) << 4));       \
      i32x4 hh = *(const i32x4*)(bbase + ((wc * 64 + ni * 32) << 4) + 2048);\
      bF[ni] = __builtin_shufflevector(lo, hh, 0, 1, 2, 3, 4, 5, 6, 7);     \
    }                                                                       \
    _Pragma("unroll")                                                       \
    for (int mi = 0; mi < 2; ++mi)                                          \
      _Pragma("unroll")                                                     \
      for (int ni = 0; ni < 2; ++ni)                                        \
        acc[mi][ni] = __builtin_amdgcn_mfma_scale_f32_32x32x64_f8f6f4(      \
            aF[mi], bF[ni], acc[mi][ni], 0, 0, 0, SB_UNIT, 0, (SB));        \
  } while (0)

// ---------- dual-phase GEMM: cross (ct -> regs) then logits+softmax --------
__global__ __launch_bounds__(256, 3) void k_dual(
    const unsigned char* __restrict__ Atg, const unsigned char* __restrict__ Cbb,
    const unsigned char* __restrict__ Ahs, const unsigned char* __restrict__ Wtb,
    const float* __restrict__ csq, const float* __restrict__ bias,
    const int* __restrict__ counter,
    float* __restrict__ pm, float* __restrict__ pl, float* __restrict__ ps) {
  const int n = *counter;
  int tilex, tiley;
  tile_map(&tilex, &tiley);
  if (tilex * MT >= n) return;

  __shared__ __align__(16) unsigned char sA[2][8192];
  __shared__ __align__(16) unsigned char sB[2][8192];

  const int t = threadIdx.x;
  const int w = t >> 6, lane = t & 63;
  const int wr = w >> 1, wc = w & 1;
  const int hi32 = lane >> 5, lc32 = lane & 31;
  const int rb = (hi32 << 12) + (lc32 << 4);     // half*4096 + row_lane*16
  const size_t Aoff = (size_t)tilex * SLAB;
  const size_t Boff = (size_t)tiley * SLAB;

  const f32x16 fz = {0.f, 0.f, 0.f, 0.f, 0.f, 0.f, 0.f, 0.f,
                     0.f, 0.f, 0.f, 0.f, 0.f, 0.f, 0.f, 0.f};
  f32x16 acc[2][2];
  #pragma unroll
  for (int mi = 0; mi < 2; ++mi)
    #pragma unroll
    for (int ni = 0; ni < 2; ++ni) acc[mi][ni] = fz;

  // ---------------- phase 1: ct = csq - 2 * (tg x codebook^T) --------------
  ISSUE(Atg, Cbb, 0, 0);
  #pragma unroll
  for (int kc = 0; kc < NKC; ++kc) {
    const int cur = kc & 1;
    if (kc + 1 < NKC) ISSUE(Atg, Cbb, kc + 1, cur ^ 1);
    else              ISSUE(Ahs, Wtb, 0, 0);      // phase-boundary prefetch
    wait_vm4();
    barrier_raw();
    COMPUTE_KC(cur, SB_UNIT);
    barrier_raw();
  }

  // pack ct into bf16-pair registers (no memory round trip)
  unsigned ctp[2][2][8];
  {
    float cqc[2];
    #pragma unroll
    for (int ni = 0; ni < 2; ++ni)
      cqc[ni] = csq[tiley * NTILE + wc * 64 + ni * 32 + lc32] - CTC;
    #pragma unroll
    for (int mi = 0; mi < 2; ++mi)
      #pragma unroll
      for (int ni = 0; ni < 2; ++ni) {
        #pragma unroll
        for (int rp = 0; rp < 8; ++rp) {
          const float v0 = cqc[ni] - 2.f * acc[mi][ni][2 * rp];
          const float v1 = cqc[ni] - 2.f * acc[mi][ni][2 * rp + 1];
          ctp[mi][ni][rp] = (unsigned)f2bf(v0) | ((unsigned)f2bf(v1) << 16);
        }
        acc[mi][ni] = fz;
      }
  }

  // ---------------- phase 2: logits = hs x W^T (W scale folded as 2^-4) ----
  #pragma unroll
  for (int kc = 0; kc < NKC; ++kc) {
    const int cur = kc & 1;
    if (kc + 1 < NKC) { ISSUE(Ahs, Wtb, kc + 1, cur ^ 1); wait_vm4(); }
    else              { wait_vm0(); }
    barrier_raw();
    COMPUTE_KC(cur, SB_W);
    barrier_raw();
  }

  // ---------------- fused softmax epilogue per 64-col strip ----------------
  float bv[2];
  #pragma unroll
  for (int ni = 0; ni < 2; ++ni)
    bv[ni] = bias[tiley * NTILE + wc * 64 + ni * 32 + lc32];

  const int chunk = tiley * 2 + wc;
  #pragma unroll
  for (int mi = 0; mi < 2; ++mi) {
    #pragma unroll
    for (int r = 0; r < 16; ++r) {
      float lg[2], ct[2];
      #pragma unroll
      for (int ni = 0; ni < 2; ++ni) {
        lg[ni] = acc[mi][ni][r] + bv[ni];
        ct[ni] = bf2f((unsigned short)((ctp[mi][ni][r >> 1] >> ((r & 1) * 16)) & 0xFFFFu));
      }
      float tmax = fmaxf(lg[0], lg[1]);
      #pragma unroll
      for (int d = 1; d < 32; d <<= 1) tmax = fmaxf(tmax, __shfl_xor(tmax, d));
      float le = 0.f, se = 0.f;
      #pragma unroll
      for (int ni = 0; ni < 2; ++ni) {
        const float e = __expf(lg[ni] - tmax);
        le += e; se += e * ct[ni];
      }
      #pragma unroll
      for (int d = 1; d < 32; d <<= 1) {
        le += __shfl_xor(le, d);
        se += __shfl_xor(se, d);
      }
      if (lc32 == 0) {
        // 32x32 C/D: row = (r&3) + 8*(r>>2) + 4*(lane>>5), col = lane&31
        const int row = tilex * MT + wr * 64 + mi * 32 + 4 * hi32 + (r & 3) + 8 * (r >> 2);
        pm[chunk * NTOK + row] = tmax;
        pl[chunk * NTOK + row] = le;
        ps[chunk * NTOK + row] = se;
      }
    }
  }
}

// -------- merge strip partials -> scalar loss (last block finalizes) -------
// 128 blocks: 64 tokens x 4 strip-quarters per block; softmax partials
// (M,L,S) merge associatively: M=max Mi; L=sum Li e^{Mi-M}; S likewise.
__global__ __launch_bounds__(256) void k_merge(
    const int* __restrict__ counter, const float* __restrict__ tsq,
    const float* __restrict__ pm, const float* __restrict__ pl,
    const float* __restrict__ ps, float* __restrict__ lsum,
    int* __restrict__ done, float* __restrict__ out) {
  const int n = *counter;
  const int tl = threadIdx.x & 63, jq = threadIdx.x >> 6;
  const int ga = blockIdx.x * 64 + tl;
  float M = -1e30f, L = 0.f, S = 0.f;
  #pragma unroll 4
  for (int j = jq * 32; j < jq * 32 + 32; ++j) M = fmaxf(M, pm[j * NTOK + ga]);
  #pragma unroll 4
  for (int j = jq * 32; j < jq * 32 + 32; ++j) {
    const float e = __expf(pm[j * NTOK + ga] - M);
    L += pl[j * NTOK + ga] * e;
    S += ps[j * NTOK + ga] * e;
  }
  __shared__ float sM[4][64], sL[4][64], sS[4][64];
  sM[jq][tl] = M; sL[jq][tl] = L; sS[jq][tl] = S;
  __syncthreads();
  if (jq == 0) {
    float Mm = fmaxf(fmaxf(sM[0][tl], sM[1][tl]), fmaxf(sM[2][tl], sM[3][tl]));
    float Lt = 0.f, St = 0.f;
    #pragma unroll
    for (int q = 0; q < 4; ++q) {
      const float e = __expf(sM[q][tl] - Mm);
      Lt += sL[q][tl] * e;
      St += sS[q][tl] * e;
    }
    float val = 0.f;
    if (ga < n) val = (tsq[ga] + CTC + St / Lt) * (LOSSW / (float)H);
    #pragma unroll
    for (int d = 1; d < 64; d <<= 1) val += __shfl_xor(val, d);
    if (tl == 0) {
      atomicAdd(lsum, val);
      __threadfence();
      const int tk = atomicAdd(done, 1);
      if (tk == (int)gridDim.x - 1) {
        __threadfence();
        out[0] = atomicAdd(lsum, 0.0f);   // atomic read-back = final sum
      }
    }
  }
}

// ---------------------------------------------------------------------------
extern "C" void kernel_launch(void* const* d_in, const int* in_sizes, int n_in,
                              void* d_out, int out_size, void* d_ws, size_t ws_size,
                              hipStream_t stream) {
  const float* hs   = (const float*)d_in[0];
  const int*   ids  = (const int*)d_in[1];
  const float* tg   = (const float*)d_in[2];
  const float* cb   = (const float*)d_in[3];
  const float* W    = (const float*)d_in[4];
  const float* bias = (const float*)d_in[5];

  char* ws = (char*)d_ws;
  constexpr size_t OFF_CSQ  = 0;                       // f32[8192] (zeroed)
  constexpr size_t OFF_TSQ  = 32768;                   // f32[8192] (zeroed)
  constexpr size_t OFF_CNT  = 65536;                   // int (zeroed)
  constexpr size_t OFF_DONE = 65540;                   // int (zeroed)
  constexpr size_t OFF_LSUM = 65544;                   // f32 (zeroed)
  constexpr size_t ZERO_BYTES = 65548;
  constexpr size_t OFF_LIST = 65664;                   // int[8192]
  constexpr size_t OFF_AHS  = 98432;                   // fp8 slab 8 MiB
  constexpr size_t OFF_ATG  = OFF_AHS + (size_t)NTOK * H;
  constexpr size_t OFF_WTB  = OFF_ATG + (size_t)NTOK * H;
  constexpr size_t OFF_CBB  = OFF_WTB + (size_t)CBN * H;
  constexpr size_t OFF_PM   = OFF_CBB + (size_t)CBN * H;
  constexpr size_t OFF_PL   = OFF_PM + (size_t)NCHK * NTOK * 4;
  constexpr size_t OFF_PS   = OFF_PL + (size_t)NCHK * NTOK * 4;

  float*          csq  = (float*)(ws + OFF_CSQ);
  float*          tsq  = (float*)(ws + OFF_TSQ);
  int*            cnt  = (int*)(ws + OFF_CNT);
  int*            done = (int*)(ws + OFF_DONE);
  float*          lsum = (float*)(ws + OFF_LSUM);
  int*            list = (int*)(ws + OFF_LIST);
  unsigned char*  Ahs  = (unsigned char*)(ws + OFF_AHS);
  unsigned char*  Atg  = (unsigned char*)(ws + OFF_ATG);
  unsigned char*  Wtb  = (unsigned char*)(ws + OFF_WTB);
  unsigned char*  Cbb  = (unsigned char*)(ws + OFF_CBB);
  float*          pm   = (float*)(ws + OFF_PM);
  float*          pl   = (float*)(ws + OFF_PL);
  float*          ps   = (float*)(ws + OFF_PS);

  hipMemsetAsync(ws, 0, ZERO_BYTES, stream);

  k_prep1<<<1312, 256, 0, stream>>>(ids, cb, W, list, cnt, csq, Wtb, Cbb);
  k_prep_a<<<256, 256, 0, stream>>>(hs, tg, list, cnt, Ahs, Atg, tsq);
  k_dual<<<dim3(64, 64), 256, 0, stream>>>(Atg, Cbb, Ahs, Wtb, csq, bias, cnt,
                                           pm, pl, ps);
  k_merge<<<NTOK / 64, 256, 0, stream>>>(cnt, tsq, pm, pl, ps, lsum, done,
                                         (float*)d_out);
}

// Round 2
// 920.325 us; speedup vs baseline: 1.0048x; 1.0048x over previous
//
#include <hip/hip_runtime.h>
#include <hip/hip_bf16.h>

// ---------------------------------------------------------------------------
// TokenDiscrepancyLoss: loss = 0.1 * sum_{mask} [ (||t||^2 + sum_c p_c (||c||^2 - 2 t.c)) / H ]
// with p = softmax(hs @ W + b) over C=8192.
//
// R8: identical to R7 (MX-scaled fp8 32x32x64 MFMA) except k_dual's
// __launch_bounds__ min-waves 3 -> 2. R7's (256,3) capped the allocator at
// ~168 VGPR while the MX port's live set (4x v16f32 acc + 2x v8i32 A/B
// tuples + 32-reg ctp) is ~150-165 -> per-iteration accumulator spills:
// WRITE_SIZE 1.57 GB/dispatch of scratch traffic, MfmaUtil 3.8%.
// (256,2) gives the allocator 256 VGPRs; actual use ~160-190 so runtime
// occupancy can still hit 3 waves/SIMD.
// Dispatches: memset, prep1, prep_a, k_dual, k_merge (5 total).
// ---------------------------------------------------------------------------

#define H        1024
#define CBN      8192
#define NTOK     8192
#define MT       128
#define NTILE    128
#define BK       64
#define NKC      16               // H / BK
#define NCHK     128              // partial strips (one per 64-col wave tile)
#define LOSSW    0.1f
#define CTC      1024.0f          // centering for bf16 ct registers
#define WSCALE   16.0f            // W pre-scale (pow2) for fp8 range
#define SB_UNIT  127              // e8m0 scale = 2^0
#define SB_W     123              // e8m0 scale = 2^-4 (undoes WSCALE)
#define SLAB     131072           // bytes per 128-row panel: 16kc*8KB

typedef __attribute__((ext_vector_type(4)))  int   i32x4;
typedef __attribute__((ext_vector_type(8)))  int   i32x8;
typedef __attribute__((ext_vector_type(16))) float f32x16;

__device__ __forceinline__ unsigned short f2bf(float f) {
  union { float f; unsigned u; } x; x.f = f;
  return (unsigned short)((x.u + 0x7FFFu + ((x.u >> 16) & 1u)) >> 16); // RNE
}
__device__ __forceinline__ float bf2f(unsigned short u) {
  union { unsigned u; float f; } x; x.u = (unsigned)u << 16;
  return x.f;
}

// ---- fp32 -> fp8 e4m3fn (OCP) ----
__device__ unsigned char f2fp8_sw(float f) {
  float a = fabsf(f);
  unsigned s = f < 0.f ? 0x80u : 0u;
  if (!(a < 448.f)) return (unsigned char)(s | 0x7Eu);
  if (a < 0.0009765625f) return (unsigned char)s;
  int e; float m = frexpf(a, &e);
  int te = e - 1;
  if (te < -6) {
    int q = (int)rintf(a * 512.f); if (q > 7) q = 7;
    return (unsigned char)(s | q);
  }
  int q = (int)rintf((2.f * m - 1.f) * 8.f);
  int E = te + 7, M = q;
  if (q == 8) { E += 1; M = 0; }
  if (E > 15) return (unsigned char)(s | 0x7Eu);
  return (unsigned char)(s | (E << 3) | M);
}
__device__ __forceinline__ unsigned pack4(float a, float b, float c, float d) {
#if __has_builtin(__builtin_amdgcn_cvt_pk_fp8_f32)
  int r = __builtin_amdgcn_cvt_pk_fp8_f32(a, b, 0, false);
  r     = __builtin_amdgcn_cvt_pk_fp8_f32(c, d, r, true);
  return (unsigned)r;
#else
  return (unsigned)f2fp8_sw(a) | ((unsigned)f2fp8_sw(b) << 8) |
         ((unsigned)f2fp8_sw(c) << 16) | ((unsigned)f2fp8_sw(d) << 24);
#endif
}

// kc-chunk internal offset for (row c, local k octet g in [0,8)):
//   half = g>>2 (k>>5), b4 = (g>>1)&1 ((k>>4)&1), lo8 = (g&1)*8 (k&8)
//   off  = half*4096 + b4*2048 + c*16 + lo8
__device__ __forceinline__ int slab_off(int g, int c) {
  return ((g >> 2) << 12) + (((g >> 1) & 1) << 11) + (c << 4) + ((g & 1) << 3);
}

// async global->LDS DMA, 16B/lane; LDS dest = wave-uniform base + lane*16
__device__ __forceinline__ void load_lds16(const void* g, void* l) {
  __builtin_amdgcn_global_load_lds((const __attribute__((address_space(1))) void*)g,
                                   (__attribute__((address_space(3))) void*)l,
                                   16, 0, 0);
}
__device__ __forceinline__ void wait_vm4() { asm volatile("s_waitcnt vmcnt(4)" ::: "memory"); }
__device__ __forceinline__ void wait_vm0() { asm volatile("s_waitcnt vmcnt(0)" ::: "memory"); }
__device__ __forceinline__ void barrier_raw() { asm volatile("s_barrier" ::: "memory"); }

// XCD-aware tile mapping
__device__ __forceinline__ void tile_map(int* tilex, int* tiley) {
  const int flat = blockIdx.y * 64 + blockIdx.x;
  const int xcd = flat & 7, loc = flat >> 3;
  *tiley = xcd * 8 + (loc & 7);
  *tilex = loc >> 3;
}

// ---------------- prep1: compact (32 blk) + W (1024 blk) + cb (256 blk) ----
__global__ __launch_bounds__(256) void k_prep1(
    const int* __restrict__ ids, const float* __restrict__ cb,
    const float* __restrict__ W,
    int* __restrict__ list, int* __restrict__ counter,
    float* __restrict__ csq,
    unsigned char* __restrict__ Wtb, unsigned char* __restrict__ Cbb) {
  __shared__ __align__(16) unsigned char tile[8192];
  const int b = blockIdx.x, t = threadIdx.x;
  if (b < 32) {
    int f = 0;
    #pragma unroll
    for (int j = 0; j < 16; ++j) f |= ids[2 * (t * 16 + j) + 1];
    int anyodd = __syncthreads_or(f);
    int i = b * 256 + t;
    int v = anyodd ? ids[i] : ids[2 * i];
    bool act = (v == 1);
    unsigned long long mask = __ballot(act);
    int lane = t & 63;
    int base = 0;
    if (lane == 0) base = atomicAdd(counter, __popcll(mask));
    base = __shfl(base, 0);
    if (act) list[base + __popcll(mask & ((1ull << lane) - 1ull))] = i;
  } else if (b < 1056) {
    // W [H][C] fp32 -> fp8 slab [tiley][kc][half][b4][c][16], scaled x16
    const int q = b - 32, tiley = q >> 4, kc = q & 15;
    const int c = t & 127, gh = t >> 7;
    unsigned char* dst = Wtb + (size_t)tiley * SLAB + (size_t)kc * 8192;
    #pragma unroll
    for (int gi = 0; gi < 4; ++gi) {
      const int g = gh * 4 + gi;
      const float* wp = W + (size_t)(kc * 64 + g * 8) * CBN + tiley * 128 + c;
      float v[8];
      #pragma unroll
      for (int j = 0; j < 8; ++j) v[j] = wp[(size_t)j * CBN] * WSCALE;
      uint2 pk;
      pk.x = pack4(v[0], v[1], v[2], v[3]);
      pk.y = pack4(v[4], v[5], v[6], v[7]);
      *(uint2*)(dst + slab_off(g, c)) = pk;
    }
  } else {
    // codebook [C][H] fp32 -> fp8 slab + csq partials
    const int q = b - 1056, tiley = q >> 2, kcg = q & 3;
    const int r = t >> 1, h = t & 1;
    const int c = tiley * 128 + r;
    float ss = 0.f;
    for (int kk = 0; kk < 4; ++kk) {
      const int kc = kcg * 4 + kk;
      const float4* s4 = (const float4*)(cb + (size_t)c * H + kc * 64 + h * 32);
      #pragma unroll
      for (int i = 0; i < 4; ++i) {
        float4 va = s4[2 * i], vb = s4[2 * i + 1];
        ss += va.x * va.x + va.y * va.y + va.z * va.z + va.w * va.w;
        ss += vb.x * vb.x + vb.y * vb.y + vb.z * vb.z + vb.w * vb.w;
        uint2 pk;
        pk.x = pack4(va.x, va.y, va.z, va.w);
        pk.y = pack4(vb.x, vb.y, vb.z, vb.w);
        *(uint2*)&tile[slab_off(h * 4 + i, r)] = pk;
      }
      __syncthreads();
      const uint4* tp = (const uint4*)tile;
      uint4 x0 = tp[t * 2], x1 = tp[t * 2 + 1];
      unsigned char* dst = Cbb + (size_t)tiley * SLAB + (size_t)kc * 8192 + t * 32;
      *(uint4*)dst = x0; *(uint4*)(dst + 16) = x1;
      __syncthreads();
    }
    ss += __shfl_xor(ss, 1);
    if (h == 0) atomicAdd(&csq[c], ss);
  }
}

// ------- gather active tokens -> fp8 slabs (hs, tg) + fp32 ||t||^2 ---------
__global__ __launch_bounds__(256) void k_prep_a(
    const float* __restrict__ hs, const float* __restrict__ tg,
    const int* __restrict__ list, const int* __restrict__ counter,
    unsigned char* __restrict__ Ahs, unsigned char* __restrict__ Atg,
    float* __restrict__ tsq) {
  const int n = *counter;
  const int n_pad = (n + MT - 1) & ~(MT - 1);
  const int tilex = blockIdx.x >> 2, kcg = blockIdx.x & 3;
  if (tilex * MT >= n_pad) return;
  __shared__ int stok[128];
  __shared__ __align__(16) unsigned char tile[8192];
  const int t = threadIdx.x, r = t >> 1, h = t & 1;
  if (t < 128) {
    int ga = tilex * MT + t;
    stok[t] = list[(ga < n) ? ga : 0];
  }
  __syncthreads();
  const size_t srow = (size_t)stok[r] * H;
  float ss = 0.f;
  for (int kk = 0; kk < 4; ++kk) {
    const int kc = kcg * 4 + kk;
    {
      const float4* s4 = (const float4*)(hs + srow + kc * 64 + h * 32);
      #pragma unroll
      for (int i = 0; i < 4; ++i) {
        float4 va = s4[2 * i], vb = s4[2 * i + 1];
        uint2 pk;
        pk.x = pack4(va.x, va.y, va.z, va.w);
        pk.y = pack4(vb.x, vb.y, vb.z, vb.w);
        *(uint2*)&tile[slab_off(h * 4 + i, r)] = pk;
      }
      __syncthreads();
      const uint4* tp = (const uint4*)tile;
      uint4 x0 = tp[t * 2], x1 = tp[t * 2 + 1];
      unsigned char* dst = Ahs + (size_t)tilex * SLAB + (size_t)kc * 8192 + t * 32;
      *(uint4*)dst = x0; *(uint4*)(dst + 16) = x1;
      __syncthreads();
    }
    {
      const float4* s4 = (const float4*)(tg + srow + kc * 64 + h * 32);
      #pragma unroll
      for (int i = 0; i < 4; ++i) {
        float4 va = s4[2 * i], vb = s4[2 * i + 1];
        ss += va.x * va.x + va.y * va.y + va.z * va.z + va.w * va.w;
        ss += vb.x * vb.x + vb.y * vb.y + vb.z * vb.z + vb.w * vb.w;
        uint2 pk;
        pk.x = pack4(va.x, va.y, va.z, va.w);
        pk.y = pack4(vb.x, vb.y, vb.z, vb.w);
        *(uint2*)&tile[slab_off(h * 4 + i, r)] = pk;
      }
      __syncthreads();
      const uint4* tp = (const uint4*)tile;
      uint4 x0 = tp[t * 2], x1 = tp[t * 2 + 1];
      unsigned char* dst = Atg + (size_t)tilex * SLAB + (size_t)kc * 8192 + t * 32;
      *(uint4*)dst = x0; *(uint4*)(dst + 16) = x1;
      __syncthreads();
    }
  }
  ss += __shfl_xor(ss, 1);
  if (h == 0) atomicAdd(&tsq[tilex * MT + r], ss);
}

// per-wave DMA batch: 4 contiguous 1 KB wave-loads (2 A granule-rows + 2 B)
#define ISSUE(Aslab, Bslab, kc, pb)                                        \
  do {                                                                     \
    const unsigned char* ap_ = (Aslab) + Aoff + (size_t)(kc) * 8192 + lane * 16; \
    const unsigned char* bp_ = (Bslab) + Boff + (size_t)(kc) * 8192 + lane * 16; \
    load_lds16(ap_ + w * 1024,       &sA[pb][w * 1024]);                   \
    load_lds16(ap_ + (w + 4) * 1024, &sA[pb][(w + 4) * 1024]);             \
    load_lds16(bp_ + w * 1024,       &sB[pb][w * 1024]);                   \
    load_lds16(bp_ + (w + 4) * 1024, &sB[pb][(w + 4) * 1024]);             \
  } while (0)

// one kc compute step: 4 MX-scaled 32x32x64 fp8 MFMA from buffer `cur`.
// Per-lane operand: 32 contiguous k-bytes = one MX block:
//   row = lane&31, k = (lane>>5)*32 + [0..31]
// -> two conflict-free stride-16B ds_read_b128 (b4=0 at +0, b4=1 at +2048).
#define COMPUTE_KC(cur, SB)                                                 \
  do {                                                                      \
    const unsigned char* abase = &sA[cur][rb];                              \
    const unsigned char* bbase = &sB[cur][rb];                              \
    i32x8 aF[2], bF[2];                                                     \
    _Pragma("unroll")                                                       \
    for (int mi = 0; mi < 2; ++mi) {                                        \
      i32x4 lo = *(const i32x4*)(abase + ((wr * 64 + mi * 32) << 4));       \
      i32x4 hh = *(const i32x4*)(abase + ((wr * 64 + mi * 32) << 4) + 2048);\
      aF[mi] = __builtin_shufflevector(lo, hh, 0, 1, 2, 3, 4, 5, 6, 7);     \
    }                                                                       \
    _Pragma("unroll")                                                       \
    for (int ni = 0; ni < 2; ++ni) {                                        \
      i32x4 lo = *(const i32x4*)(bbase + ((wc * 64 + ni * 32) << 4));       \
      i32x4 hh = *(const i32x4*)(bbase + ((wc * 64 + ni * 32) << 4) + 2048);\
      bF[ni] = __builtin_shufflevector(lo, hh, 0, 1, 2, 3, 4, 5, 6, 7);     \
    }                                                                       \
    _Pragma("unroll")                                                       \
    for (int mi = 0; mi < 2; ++mi)                                          \
      _Pragma("unroll")                                                     \
      for (int ni = 0; ni < 2; ++ni)                                        \
        acc[mi][ni] = __builtin_amdgcn_mfma_scale_f32_32x32x64_f8f6f4(      \
            aF[mi], bF[ni], acc[mi][ni], 0, 0, 0, SB_UNIT, 0, (SB));        \
  } while (0)

// ---------- dual-phase GEMM: cross (ct -> regs) then logits+softmax --------
__global__ __launch_bounds__(256, 2) void k_dual(
    const unsigned char* __restrict__ Atg, const unsigned char* __restrict__ Cbb,
    const unsigned char* __restrict__ Ahs, const unsigned char* __restrict__ Wtb,
    const float* __restrict__ csq, const float* __restrict__ bias,
    const int* __restrict__ counter,
    float* __restrict__ pm, float* __restrict__ pl, float* __restrict__ ps) {
  const int n = *counter;
  int tilex, tiley;
  tile_map(&tilex, &tiley);
  if (tilex * MT >= n) return;

  __shared__ __align__(16) unsigned char sA[2][8192];
  __shared__ __align__(16) unsigned char sB[2][8192];

  const int t = threadIdx.x;
  const int w = t >> 6, lane = t & 63;
  const int wr = w >> 1, wc = w & 1;
  const int hi32 = lane >> 5, lc32 = lane & 31;
  const int rb = (hi32 << 12) + (lc32 << 4);     // half*4096 + row_lane*16
  const size_t Aoff = (size_t)tilex * SLAB;
  const size_t Boff = (size_t)tiley * SLAB;

  const f32x16 fz = {0.f, 0.f, 0.f, 0.f, 0.f, 0.f, 0.f, 0.f,
                     0.f, 0.f, 0.f, 0.f, 0.f, 0.f, 0.f, 0.f};
  f32x16 acc[2][2];
  #pragma unroll
  for (int mi = 0; mi < 2; ++mi)
    #pragma unroll
    for (int ni = 0; ni < 2; ++ni) acc[mi][ni] = fz;

  // ---------------- phase 1: ct = csq - 2 * (tg x codebook^T) --------------
  ISSUE(Atg, Cbb, 0, 0);
  #pragma unroll
  for (int kc = 0; kc < NKC; ++kc) {
    const int cur = kc & 1;
    if (kc + 1 < NKC) ISSUE(Atg, Cbb, kc + 1, cur ^ 1);
    else              ISSUE(Ahs, Wtb, 0, 0);      // phase-boundary prefetch
    wait_vm4();
    barrier_raw();
    COMPUTE_KC(cur, SB_UNIT);
    barrier_raw();
  }

  // pack ct into bf16-pair registers (no memory round trip)
  unsigned ctp[2][2][8];
  {
    float cqc[2];
    #pragma unroll
    for (int ni = 0; ni < 2; ++ni)
      cqc[ni] = csq[tiley * NTILE + wc * 64 + ni * 32 + lc32] - CTC;
    #pragma unroll
    for (int mi = 0; mi < 2; ++mi)
      #pragma unroll
      for (int ni = 0; ni < 2; ++ni) {
        #pragma unroll
        for (int rp = 0; rp < 8; ++rp) {
          const float v0 = cqc[ni] - 2.f * acc[mi][ni][2 * rp];
          const float v1 = cqc[ni] - 2.f * acc[mi][ni][2 * rp + 1];
          ctp[mi][ni][rp] = (unsigned)f2bf(v0) | ((unsigned)f2bf(v1) << 16);
        }
        acc[mi][ni] = fz;
      }
  }

  // ---------------- phase 2: logits = hs x W^T (W scale folded as 2^-4) ----
  #pragma unroll
  for (int kc = 0; kc < NKC; ++kc) {
    const int cur = kc & 1;
    if (kc + 1 < NKC) { ISSUE(Ahs, Wtb, kc + 1, cur ^ 1); wait_vm4(); }
    else              { wait_vm0(); }
    barrier_raw();
    COMPUTE_KC(cur, SB_W);
    barrier_raw();
  }

  // ---------------- fused softmax epilogue per 64-col strip ----------------
  float bv[2];
  #pragma unroll
  for (int ni = 0; ni < 2; ++ni)
    bv[ni] = bias[tiley * NTILE + wc * 64 + ni * 32 + lc32];

  const int chunk = tiley * 2 + wc;
  #pragma unroll
  for (int mi = 0; mi < 2; ++mi) {
    #pragma unroll
    for (int r = 0; r < 16; ++r) {
      float lg[2], ct[2];
      #pragma unroll
      for (int ni = 0; ni < 2; ++ni) {
        lg[ni] = acc[mi][ni][r] + bv[ni];
        ct[ni] = bf2f((unsigned short)((ctp[mi][ni][r >> 1] >> ((r & 1) * 16)) & 0xFFFFu));
      }
      float tmax = fmaxf(lg[0], lg[1]);
      #pragma unroll
      for (int d = 1; d < 32; d <<= 1) tmax = fmaxf(tmax, __shfl_xor(tmax, d));
      float le = 0.f, se = 0.f;
      #pragma unroll
      for (int ni = 0; ni < 2; ++ni) {
        const float e = __expf(lg[ni] - tmax);
        le += e; se += e * ct[ni];
      }
      #pragma unroll
      for (int d = 1; d < 32; d <<= 1) {
        le += __shfl_xor(le, d);
        se += __shfl_xor(se, d);
      }
      if (lc32 == 0) {
        // 32x32 C/D: row = (r&3) + 8*(r>>2) + 4*(lane>>5), col = lane&31
        const int row = tilex * MT + wr * 64 + mi * 32 + 4 * hi32 + (r & 3) + 8 * (r >> 2);
        pm[chunk * NTOK + row] = tmax;
        pl[chunk * NTOK + row] = le;
        ps[chunk * NTOK + row] = se;
      }
    }
  }
}

// -------- merge strip partials -> scalar loss (last block finalizes) -------
// 128 blocks: 64 tokens x 4 strip-quarters per block; softmax partials
// (M,L,S) merge associatively: M=max Mi; L=sum Li e^{Mi-M}; S likewise.
__global__ __launch_bounds__(256) void k_merge(
    const int* __restrict__ counter, const float* __restrict__ tsq,
    const float* __restrict__ pm, const float* __restrict__ pl,
    const float* __restrict__ ps, float* __restrict__ lsum,
    int* __restrict__ done, float* __restrict__ out) {
  const int n = *counter;
  const int tl = threadIdx.x & 63, jq = threadIdx.x >> 6;
  const int ga = blockIdx.x * 64 + tl;
  float M = -1e30f, L = 0.f, S = 0.f;
  #pragma unroll 4
  for (int j = jq * 32; j < jq * 32 + 32; ++j) M = fmaxf(M, pm[j * NTOK + ga]);
  #pragma unroll 4
  for (int j = jq * 32; j < jq * 32 + 32; ++j) {
    const float e = __expf(pm[j * NTOK + ga] - M);
    L += pl[j * NTOK + ga] * e;
    S += ps[j * NTOK + ga] * e;
  }
  __shared__ float sM[4][64], sL[4][64], sS[4][64];
  sM[jq][tl] = M; sL[jq][tl] = L; sS[jq][tl] = S;
  __syncthreads();
  if (jq == 0) {
    float Mm = fmaxf(fmaxf(sM[0][tl], sM[1][tl]), fmaxf(sM[2][tl], sM[3][tl]));
    float Lt = 0.f, St = 0.f;
    #pragma unroll
    for (int q = 0; q < 4; ++q) {
      const float e = __expf(sM[q][tl] - Mm);
      Lt += sL[q][tl] * e;
      St += sS[q][tl] * e;
    }
    float val = 0.f;
    if (ga < n) val = (tsq[ga] + CTC + St / Lt) * (LOSSW / (float)H);
    #pragma unroll
    for (int d = 1; d < 64; d <<= 1) val += __shfl_xor(val, d);
    if (tl == 0) {
      atomicAdd(lsum, val);
      __threadfence();
      const int tk = atomicAdd(done, 1);
      if (tk == (int)gridDim.x - 1) {
        __threadfence();
        out[0] = atomicAdd(lsum, 0.0f);   // atomic read-back = final sum
      }
    }
  }
}

// ---------------------------------------------------------------------------
extern "C" void kernel_launch(void* const* d_in, const int* in_sizes, int n_in,
                              void* d_out, int out_size, void* d_ws, size_t ws_size,
                              hipStream_t stream) {
  const float* hs   = (const float*)d_in[0];
  const int*   ids  = (const int*)d_in[1];
  const float* tg   = (const float*)d_in[2];
  const float* cb   = (const float*)d_in[3];
  const float* W    = (const float*)d_in[4];
  const float* bias = (const float*)d_in[5];

  char* ws = (char*)d_ws;
  constexpr size_t OFF_CSQ  = 0;                       // f32[8192] (zeroed)
  constexpr size_t OFF_TSQ  = 32768;                   // f32[8192] (zeroed)
  constexpr size_t OFF_CNT  = 65536;                   // int (zeroed)
  constexpr size_t OFF_DONE = 65540;                   // int (zeroed)
  constexpr size_t OFF_LSUM = 65544;                   // f32 (zeroed)
  constexpr size_t ZERO_BYTES = 65548;
  constexpr size_t OFF_LIST = 65664;                   // int[8192]
  constexpr size_t OFF_AHS  = 98432;                   // fp8 slab 8 MiB
  constexpr size_t OFF_ATG  = OFF_AHS + (size_t)NTOK * H;
  constexpr size_t OFF_WTB  = OFF_ATG + (size_t)NTOK * H;
  constexpr size_t OFF_CBB  = OFF_WTB + (size_t)CBN * H;
  constexpr size_t OFF_PM   = OFF_CBB + (size_t)CBN * H;
  constexpr size_t OFF_PL   = OFF_PM + (size_t)NCHK * NTOK * 4;
  constexpr size_t OFF_PS   = OFF_PL + (size_t)NCHK * NTOK * 4;

  float*          csq  = (float*)(ws + OFF_CSQ);
  float*          tsq  = (float*)(ws + OFF_TSQ);
  int*            cnt  = (int*)(ws + OFF_CNT);
  int*            done = (int*)(ws + OFF_DONE);
  float*          lsum = (float*)(ws + OFF_LSUM);
  int*            list = (int*)(ws + OFF_LIST);
  unsigned char*  Ahs  = (unsigned char*)(ws + OFF_AHS);
  unsigned char*  Atg  = (unsigned char*)(ws + OFF_ATG);
  unsigned char*  Wtb  = (unsigned char*)(ws + OFF_WTB);
  unsigned char*  Cbb  = (unsigned char*)(ws + OFF_CBB);
  float*          pm   = (float*)(ws + OFF_PM);
  float*          pl   = (float*)(ws + OFF_PL);
  float*          ps   = (float*)(ws + OFF_PS);

  hipMemsetAsync(ws, 0, ZERO_BYTES, stream);

  k_prep1<<<1312, 256, 0, stream>>>(ids, cb, W, list, cnt, csq, Wtb, Cbb);
  k_prep_a<<<256, 256, 0, stream>>>(hs, tg, list, cnt, Ahs, Atg, tsq);
  k_dual<<<dim3(64, 64), 256, 0, stream>>>(Atg, Cbb, Ahs, Wtb, csq, bias, cnt,
                                           pm, pl, ps);
  k_merge<<<NTOK / 64, 256, 0, stream>>>(cnt, tsq, pm, pl, ps, lsum, done,
                                         (float*)d_out);
}

// Round 3
// 332.791 us; speedup vs baseline: 2.7787x; 2.7655x over previous
//
#include <hip/hip_runtime.h>
#include <hip/hip_bf16.h>

// ---------------------------------------------------------------------------
// TokenDiscrepancyLoss: loss = 0.1 * sum_{mask} [ (||t||^2 + sum_c p_c (||c||^2 - 2 t.c)) / H ]
// with p = softmax(hs @ W + b) over C=8192.
//
// R9: same MX-scaled fp8 32x32x64 k_dual as R7/R8, but the two kc loops are
// #pragma unroll 1 (runtime loops). R7/R8's full 16x unroll let the MFMA
// scheduler reassociate the 4 independent acc chains across iterations,
// keeping many v8i32 operand tuples live -> 1.4-1.6 GB/dispatch scratch
// spill traffic (2 KB/thread/phase, matching 16kc x 32 regs x 4B).
// A runtime loop makes acc a loop-carried phi: MFMAs can't cross the
// backedge, per-iteration live set ~150 VGPR, no spill.
// Dispatches: memset, prep1, prep_a, k_dual, k_merge (5 total).
// ---------------------------------------------------------------------------

#define H        1024
#define CBN      8192
#define NTOK     8192
#define MT       128
#define NTILE    128
#define BK       64
#define NKC      16               // H / BK
#define NCHK     128              // partial strips (one per 64-col wave tile)
#define LOSSW    0.1f
#define CTC      1024.0f          // centering for bf16 ct registers
#define WSCALE   16.0f            // W pre-scale (pow2) for fp8 range
#define SB_UNIT  127              // e8m0 scale = 2^0
#define SB_W     123              // e8m0 scale = 2^-4 (undoes WSCALE)
#define SLAB     131072           // bytes per 128-row panel: 16kc*8KB

typedef __attribute__((ext_vector_type(4)))  int   i32x4;
typedef __attribute__((ext_vector_type(8)))  int   i32x8;
typedef __attribute__((ext_vector_type(16))) float f32x16;

__device__ __forceinline__ unsigned short f2bf(float f) {
  union { float f; unsigned u; } x; x.f = f;
  return (unsigned short)((x.u + 0x7FFFu + ((x.u >> 16) & 1u)) >> 16); // RNE
}
__device__ __forceinline__ float bf2f(unsigned short u) {
  union { unsigned u; float f; } x; x.u = (unsigned)u << 16;
  return x.f;
}

// ---- fp32 -> fp8 e4m3fn (OCP) ----
__device__ unsigned char f2fp8_sw(float f) {
  float a = fabsf(f);
  unsigned s = f < 0.f ? 0x80u : 0u;
  if (!(a < 448.f)) return (unsigned char)(s | 0x7Eu);
  if (a < 0.0009765625f) return (unsigned char)s;
  int e; float m = frexpf(a, &e);
  int te = e - 1;
  if (te < -6) {
    int q = (int)rintf(a * 512.f); if (q > 7) q = 7;
    return (unsigned char)(s | q);
  }
  int q = (int)rintf((2.f * m - 1.f) * 8.f);
  int E = te + 7, M = q;
  if (q == 8) { E += 1; M = 0; }
  if (E > 15) return (unsigned char)(s | 0x7Eu);
  return (unsigned char)(s | (E << 3) | M);
}
__device__ __forceinline__ unsigned pack4(float a, float b, float c, float d) {
#if __has_builtin(__builtin_amdgcn_cvt_pk_fp8_f32)
  int r = __builtin_amdgcn_cvt_pk_fp8_f32(a, b, 0, false);
  r     = __builtin_amdgcn_cvt_pk_fp8_f32(c, d, r, true);
  return (unsigned)r;
#else
  return (unsigned)f2fp8_sw(a) | ((unsigned)f2fp8_sw(b) << 8) |
         ((unsigned)f2fp8_sw(c) << 16) | ((unsigned)f2fp8_sw(d) << 24);
#endif
}

// kc-chunk internal offset for (row c, local k octet g in [0,8)):
//   half = g>>2 (k>>5), b4 = (g>>1)&1 ((k>>4)&1), lo8 = (g&1)*8 (k&8)
//   off  = half*4096 + b4*2048 + c*16 + lo8
__device__ __forceinline__ int slab_off(int g, int c) {
  return ((g >> 2) << 12) + (((g >> 1) & 1) << 11) + (c << 4) + ((g & 1) << 3);
}

// async global->LDS DMA, 16B/lane; LDS dest = wave-uniform base + lane*16
__device__ __forceinline__ void load_lds16(const void* g, void* l) {
  __builtin_amdgcn_global_load_lds((const __attribute__((address_space(1))) void*)g,
                                   (__attribute__((address_space(3))) void*)l,
                                   16, 0, 0);
}
__device__ __forceinline__ void wait_vm4() { asm volatile("s_waitcnt vmcnt(4)" ::: "memory"); }
__device__ __forceinline__ void wait_vm0() { asm volatile("s_waitcnt vmcnt(0)" ::: "memory"); }
__device__ __forceinline__ void barrier_raw() { asm volatile("s_barrier" ::: "memory"); }

// XCD-aware tile mapping
__device__ __forceinline__ void tile_map(int* tilex, int* tiley) {
  const int flat = blockIdx.y * 64 + blockIdx.x;
  const int xcd = flat & 7, loc = flat >> 3;
  *tiley = xcd * 8 + (loc & 7);
  *tilex = loc >> 3;
}

// ---------------- prep1: compact (32 blk) + W (1024 blk) + cb (256 blk) ----
__global__ __launch_bounds__(256) void k_prep1(
    const int* __restrict__ ids, const float* __restrict__ cb,
    const float* __restrict__ W,
    int* __restrict__ list, int* __restrict__ counter,
    float* __restrict__ csq,
    unsigned char* __restrict__ Wtb, unsigned char* __restrict__ Cbb) {
  __shared__ __align__(16) unsigned char tile[8192];
  const int b = blockIdx.x, t = threadIdx.x;
  if (b < 32) {
    int f = 0;
    #pragma unroll
    for (int j = 0; j < 16; ++j) f |= ids[2 * (t * 16 + j) + 1];
    int anyodd = __syncthreads_or(f);
    int i = b * 256 + t;
    int v = anyodd ? ids[i] : ids[2 * i];
    bool act = (v == 1);
    unsigned long long mask = __ballot(act);
    int lane = t & 63;
    int base = 0;
    if (lane == 0) base = atomicAdd(counter, __popcll(mask));
    base = __shfl(base, 0);
    if (act) list[base + __popcll(mask & ((1ull << lane) - 1ull))] = i;
  } else if (b < 1056) {
    // W [H][C] fp32 -> fp8 slab [tiley][kc][half][b4][c][16], scaled x16
    const int q = b - 32, tiley = q >> 4, kc = q & 15;
    const int c = t & 127, gh = t >> 7;
    unsigned char* dst = Wtb + (size_t)tiley * SLAB + (size_t)kc * 8192;
    #pragma unroll
    for (int gi = 0; gi < 4; ++gi) {
      const int g = gh * 4 + gi;
      const float* wp = W + (size_t)(kc * 64 + g * 8) * CBN + tiley * 128 + c;
      float v[8];
      #pragma unroll
      for (int j = 0; j < 8; ++j) v[j] = wp[(size_t)j * CBN] * WSCALE;
      uint2 pk;
      pk.x = pack4(v[0], v[1], v[2], v[3]);
      pk.y = pack4(v[4], v[5], v[6], v[7]);
      *(uint2*)(dst + slab_off(g, c)) = pk;
    }
  } else {
    // codebook [C][H] fp32 -> fp8 slab + csq partials
    const int q = b - 1056, tiley = q >> 2, kcg = q & 3;
    const int r = t >> 1, h = t & 1;
    const int c = tiley * 128 + r;
    float ss = 0.f;
    for (int kk = 0; kk < 4; ++kk) {
      const int kc = kcg * 4 + kk;
      const float4* s4 = (const float4*)(cb + (size_t)c * H + kc * 64 + h * 32);
      #pragma unroll
      for (int i = 0; i < 4; ++i) {
        float4 va = s4[2 * i], vb = s4[2 * i + 1];
        ss += va.x * va.x + va.y * va.y + va.z * va.z + va.w * va.w;
        ss += vb.x * vb.x + vb.y * vb.y + vb.z * vb.z + vb.w * vb.w;
        uint2 pk;
        pk.x = pack4(va.x, va.y, va.z, va.w);
        pk.y = pack4(vb.x, vb.y, vb.z, vb.w);
        *(uint2*)&tile[slab_off(h * 4 + i, r)] = pk;
      }
      __syncthreads();
      const uint4* tp = (const uint4*)tile;
      uint4 x0 = tp[t * 2], x1 = tp[t * 2 + 1];
      unsigned char* dst = Cbb + (size_t)tiley * SLAB + (size_t)kc * 8192 + t * 32;
      *(uint4*)dst = x0; *(uint4*)(dst + 16) = x1;
      __syncthreads();
    }
    ss += __shfl_xor(ss, 1);
    if (h == 0) atomicAdd(&csq[c], ss);
  }
}

// ------- gather active tokens -> fp8 slabs (hs, tg) + fp32 ||t||^2 ---------
__global__ __launch_bounds__(256) void k_prep_a(
    const float* __restrict__ hs, const float* __restrict__ tg,
    const int* __restrict__ list, const int* __restrict__ counter,
    unsigned char* __restrict__ Ahs, unsigned char* __restrict__ Atg,
    float* __restrict__ tsq) {
  const int n = *counter;
  const int n_pad = (n + MT - 1) & ~(MT - 1);
  const int tilex = blockIdx.x >> 2, kcg = blockIdx.x & 3;
  if (tilex * MT >= n_pad) return;
  __shared__ int stok[128];
  __shared__ __align__(16) unsigned char tile[8192];
  const int t = threadIdx.x, r = t >> 1, h = t & 1;
  if (t < 128) {
    int ga = tilex * MT + t;
    stok[t] = list[(ga < n) ? ga : 0];
  }
  __syncthreads();
  const size_t srow = (size_t)stok[r] * H;
  float ss = 0.f;
  for (int kk = 0; kk < 4; ++kk) {
    const int kc = kcg * 4 + kk;
    {
      const float4* s4 = (const float4*)(hs + srow + kc * 64 + h * 32);
      #pragma unroll
      for (int i = 0; i < 4; ++i) {
        float4 va = s4[2 * i], vb = s4[2 * i + 1];
        uint2 pk;
        pk.x = pack4(va.x, va.y, va.z, va.w);
        pk.y = pack4(vb.x, vb.y, vb.z, vb.w);
        *(uint2*)&tile[slab_off(h * 4 + i, r)] = pk;
      }
      __syncthreads();
      const uint4* tp = (const uint4*)tile;
      uint4 x0 = tp[t * 2], x1 = tp[t * 2 + 1];
      unsigned char* dst = Ahs + (size_t)tilex * SLAB + (size_t)kc * 8192 + t * 32;
      *(uint4*)dst = x0; *(uint4*)(dst + 16) = x1;
      __syncthreads();
    }
    {
      const float4* s4 = (const float4*)(tg + srow + kc * 64 + h * 32);
      #pragma unroll
      for (int i = 0; i < 4; ++i) {
        float4 va = s4[2 * i], vb = s4[2 * i + 1];
        ss += va.x * va.x + va.y * va.y + va.z * va.z + va.w * va.w;
        ss += vb.x * vb.x + vb.y * vb.y + vb.z * vb.z + vb.w * vb.w;
        uint2 pk;
        pk.x = pack4(va.x, va.y, va.z, va.w);
        pk.y = pack4(vb.x, vb.y, vb.z, vb.w);
        *(uint2*)&tile[slab_off(h * 4 + i, r)] = pk;
      }
      __syncthreads();
      const uint4* tp = (const uint4*)tile;
      uint4 x0 = tp[t * 2], x1 = tp[t * 2 + 1];
      unsigned char* dst = Atg + (size_t)tilex * SLAB + (size_t)kc * 8192 + t * 32;
      *(uint4*)dst = x0; *(uint4*)(dst + 16) = x1;
      __syncthreads();
    }
  }
  ss += __shfl_xor(ss, 1);
  if (h == 0) atomicAdd(&tsq[tilex * MT + r], ss);
}

// per-wave DMA batch: 4 contiguous 1 KB wave-loads (2 A granule-rows + 2 B)
#define ISSUE(Aslab, Bslab, kc, pb)                                        \
  do {                                                                     \
    const unsigned char* ap_ = (Aslab) + Aoff + (size_t)(kc) * 8192 + lane * 16; \
    const unsigned char* bp_ = (Bslab) + Boff + (size_t)(kc) * 8192 + lane * 16; \
    load_lds16(ap_ + w * 1024,       &sA[pb][w * 1024]);                   \
    load_lds16(ap_ + (w + 4) * 1024, &sA[pb][(w + 4) * 1024]);             \
    load_lds16(bp_ + w * 1024,       &sB[pb][w * 1024]);                   \
    load_lds16(bp_ + (w + 4) * 1024, &sB[pb][(w + 4) * 1024]);             \
  } while (0)

// one kc compute step: 4 MX-scaled 32x32x64 fp8 MFMA from buffer `cur`.
// Per-lane operand: 32 contiguous k-bytes = one MX block:
//   row = lane&31, k = (lane>>5)*32 + [0..31]
// -> two conflict-free stride-16B ds_read_b128 (b4=0 at +0, b4=1 at +2048).
#define COMPUTE_KC(cur, SB)                                                 \
  do {                                                                      \
    const unsigned char* abase = &sA[cur][rb];                              \
    const unsigned char* bbase = &sB[cur][rb];                              \
    i32x8 aF[2], bF[2];                                                     \
    _Pragma("unroll")                                                       \
    for (int mi = 0; mi < 2; ++mi) {                                        \
      i32x4 lo = *(const i32x4*)(abase + ((wr * 64 + mi * 32) << 4));       \
      i32x4 hh = *(const i32x4*)(abase + ((wr * 64 + mi * 32) << 4) + 2048);\
      aF[mi] = __builtin_shufflevector(lo, hh, 0, 1, 2, 3, 4, 5, 6, 7);     \
    }                                                                       \
    _Pragma("unroll")                                                       \
    for (int ni = 0; ni < 2; ++ni) {                                        \
      i32x4 lo = *(const i32x4*)(bbase + ((wc * 64 + ni * 32) << 4));       \
      i32x4 hh = *(const i32x4*)(bbase + ((wc * 64 + ni * 32) << 4) + 2048);\
      bF[ni] = __builtin_shufflevector(lo, hh, 0, 1, 2, 3, 4, 5, 6, 7);     \
    }                                                                       \
    _Pragma("unroll")                                                       \
    for (int mi = 0; mi < 2; ++mi)                                          \
      _Pragma("unroll")                                                     \
      for (int ni = 0; ni < 2; ++ni)                                        \
        acc[mi][ni] = __builtin_amdgcn_mfma_scale_f32_32x32x64_f8f6f4(      \
            aF[mi], bF[ni], acc[mi][ni], 0, 0, 0, SB_UNIT, 0, (SB));        \
  } while (0)

// ---------- dual-phase GEMM: cross (ct -> regs) then logits+softmax --------
__global__ __launch_bounds__(256, 2) void k_dual(
    const unsigned char* __restrict__ Atg, const unsigned char* __restrict__ Cbb,
    const unsigned char* __restrict__ Ahs, const unsigned char* __restrict__ Wtb,
    const float* __restrict__ csq, const float* __restrict__ bias,
    const int* __restrict__ counter,
    float* __restrict__ pm, float* __restrict__ pl, float* __restrict__ ps) {
  const int n = *counter;
  int tilex, tiley;
  tile_map(&tilex, &tiley);
  if (tilex * MT >= n) return;

  __shared__ __align__(16) unsigned char sA[2][8192];
  __shared__ __align__(16) unsigned char sB[2][8192];

  const int t = threadIdx.x;
  const int w = t >> 6, lane = t & 63;
  const int wr = w >> 1, wc = w & 1;
  const int hi32 = lane >> 5, lc32 = lane & 31;
  const int rb = (hi32 << 12) + (lc32 << 4);     // half*4096 + row_lane*16
  const size_t Aoff = (size_t)tilex * SLAB;
  const size_t Boff = (size_t)tiley * SLAB;

  const f32x16 fz = {0.f, 0.f, 0.f, 0.f, 0.f, 0.f, 0.f, 0.f,
                     0.f, 0.f, 0.f, 0.f, 0.f, 0.f, 0.f, 0.f};
  f32x16 acc[2][2];
  #pragma unroll
  for (int mi = 0; mi < 2; ++mi)
    #pragma unroll
    for (int ni = 0; ni < 2; ++ni) acc[mi][ni] = fz;

  // ---------------- phase 1: ct = csq - 2 * (tg x codebook^T) --------------
  // #pragma unroll 1: a runtime loop makes acc a loop-carried phi, so the
  // MFMA scheduler cannot reassociate acc chains across iterations (the
  // full-unroll version spilled 1.4+ GB/dispatch of operand tuples).
  ISSUE(Atg, Cbb, 0, 0);
  #pragma unroll 1
  for (int kc = 0; kc < NKC; ++kc) {
    const int cur = kc & 1;
    if (kc + 1 < NKC) ISSUE(Atg, Cbb, kc + 1, cur ^ 1);
    else              ISSUE(Ahs, Wtb, 0, 0);      // phase-boundary prefetch
    wait_vm4();
    barrier_raw();
    COMPUTE_KC(cur, SB_UNIT);
    barrier_raw();
  }

  // pack ct into bf16-pair registers (no memory round trip)
  unsigned ctp[2][2][8];
  {
    float cqc[2];
    #pragma unroll
    for (int ni = 0; ni < 2; ++ni)
      cqc[ni] = csq[tiley * NTILE + wc * 64 + ni * 32 + lc32] - CTC;
    #pragma unroll
    for (int mi = 0; mi < 2; ++mi)
      #pragma unroll
      for (int ni = 0; ni < 2; ++ni) {
        #pragma unroll
        for (int rp = 0; rp < 8; ++rp) {
          const float v0 = cqc[ni] - 2.f * acc[mi][ni][2 * rp];
          const float v1 = cqc[ni] - 2.f * acc[mi][ni][2 * rp + 1];
          ctp[mi][ni][rp] = (unsigned)f2bf(v0) | ((unsigned)f2bf(v1) << 16);
        }
        acc[mi][ni] = fz;
      }
  }

  // ---------------- phase 2: logits = hs x W^T (W scale folded as 2^-4) ----
  #pragma unroll 1
  for (int kc = 0; kc < NKC; ++kc) {
    const int cur = kc & 1;
    if (kc + 1 < NKC) { ISSUE(Ahs, Wtb, kc + 1, cur ^ 1); wait_vm4(); }
    else              { wait_vm0(); }
    barrier_raw();
    COMPUTE_KC(cur, SB_W);
    barrier_raw();
  }

  // ---------------- fused softmax epilogue per 64-col strip ----------------
  float bv[2];
  #pragma unroll
  for (int ni = 0; ni < 2; ++ni)
    bv[ni] = bias[tiley * NTILE + wc * 64 + ni * 32 + lc32];

  const int chunk = tiley * 2 + wc;
  #pragma unroll
  for (int mi = 0; mi < 2; ++mi) {
    #pragma unroll
    for (int r = 0; r < 16; ++r) {
      float lg[2], ct[2];
      #pragma unroll
      for (int ni = 0; ni < 2; ++ni) {
        lg[ni] = acc[mi][ni][r] + bv[ni];
        ct[ni] = bf2f((unsigned short)((ctp[mi][ni][r >> 1] >> ((r & 1) * 16)) & 0xFFFFu));
      }
      float tmax = fmaxf(lg[0], lg[1]);
      #pragma unroll
      for (int d = 1; d < 32; d <<= 1) tmax = fmaxf(tmax, __shfl_xor(tmax, d));
      float le = 0.f, se = 0.f;
      #pragma unroll
      for (int ni = 0; ni < 2; ++ni) {
        const float e = __expf(lg[ni] - tmax);
        le += e; se += e * ct[ni];
      }
      #pragma unroll
      for (int d = 1; d < 32; d <<= 1) {
        le += __shfl_xor(le, d);
        se += __shfl_xor(se, d);
      }
      if (lc32 == 0) {
        // 32x32 C/D: row = (r&3) + 8*(r>>2) + 4*(lane>>5), col = lane&31
        const int row = tilex * MT + wr * 64 + mi * 32 + 4 * hi32 + (r & 3) + 8 * (r >> 2);
        pm[chunk * NTOK + row] = tmax;
        pl[chunk * NTOK + row] = le;
        ps[chunk * NTOK + row] = se;
      }
    }
  }
}

// -------- merge strip partials -> scalar loss (last block finalizes) -------
// 128 blocks: 64 tokens x 4 strip-quarters per block; softmax partials
// (M,L,S) merge associatively: M=max Mi; L=sum Li e^{Mi-M}; S likewise.
__global__ __launch_bounds__(256) void k_merge(
    const int* __restrict__ counter, const float* __restrict__ tsq,
    const float* __restrict__ pm, const float* __restrict__ pl,
    const float* __restrict__ ps, float* __restrict__ lsum,
    int* __restrict__ done, float* __restrict__ out) {
  const int n = *counter;
  const int tl = threadIdx.x & 63, jq = threadIdx.x >> 6;
  const int ga = blockIdx.x * 64 + tl;
  float M = -1e30f, L = 0.f, S = 0.f;
  #pragma unroll 4
  for (int j = jq * 32; j < jq * 32 + 32; ++j) M = fmaxf(M, pm[j * NTOK + ga]);
  #pragma unroll 4
  for (int j = jq * 32; j < jq * 32 + 32; ++j) {
    const float e = __expf(pm[j * NTOK + ga] - M);
    L += pl[j * NTOK + ga] * e;
    S += ps[j * NTOK + ga] * e;
  }
  __shared__ float sM[4][64], sL[4][64], sS[4][64];
  sM[jq][tl] = M; sL[jq][tl] = L; sS[jq][tl] = S;
  __syncthreads();
  if (jq == 0) {
    float Mm = fmaxf(fmaxf(sM[0][tl], sM[1][tl]), fmaxf(sM[2][tl], sM[3][tl]));
    float Lt = 0.f, St = 0.f;
    #pragma unroll
    for (int q = 0; q < 4; ++q) {
      const float e = __expf(sM[q][tl] - Mm);
      Lt += sL[q][tl] * e;
      St += sS[q][tl] * e;
    }
    float val = 0.f;
    if (ga < n) val = (tsq[ga] + CTC + St / Lt) * (LOSSW / (float)H);
    #pragma unroll
    for (int d = 1; d < 64; d <<= 1) val += __shfl_xor(val, d);
    if (tl == 0) {
      atomicAdd(lsum, val);
      __threadfence();
      const int tk = atomicAdd(done, 1);
      if (tk == (int)gridDim.x - 1) {
        __threadfence();
        out[0] = atomicAdd(lsum, 0.0f);   // atomic read-back = final sum
      }
    }
  }
}

// ---------------------------------------------------------------------------
extern "C" void kernel_launch(void* const* d_in, const int* in_sizes, int n_in,
                              void* d_out, int out_size, void* d_ws, size_t ws_size,
                              hipStream_t stream) {
  const float* hs   = (const float*)d_in[0];
  const int*   ids  = (const int*)d_in[1];
  const float* tg   = (const float*)d_in[2];
  const float* cb   = (const float*)d_in[3];
  const float* W    = (const float*)d_in[4];
  const float* bias = (const float*)d_in[5];

  char* ws = (char*)d_ws;
  constexpr size_t OFF_CSQ  = 0;                       // f32[8192] (zeroed)
  constexpr size_t OFF_TSQ  = 32768;                   // f32[8192] (zeroed)
  constexpr size_t OFF_CNT  = 65536;                   // int (zeroed)
  constexpr size_t OFF_DONE = 65540;                   // int (zeroed)
  constexpr size_t OFF_LSUM = 65544;                   // f32 (zeroed)
  constexpr size_t ZERO_BYTES = 65548;
  constexpr size_t OFF_LIST = 65664;                   // int[8192]
  constexpr size_t OFF_AHS  = 98432;                   // fp8 slab 8 MiB
  constexpr size_t OFF_ATG  = OFF_AHS + (size_t)NTOK * H;
  constexpr size_t OFF_WTB  = OFF_ATG + (size_t)NTOK * H;
  constexpr size_t OFF_CBB  = OFF_WTB + (size_t)CBN * H;
  constexpr size_t OFF_PM   = OFF_CBB + (size_t)CBN * H;
  constexpr size_t OFF_PL   = OFF_PM + (size_t)NCHK * NTOK * 4;
  constexpr size_t OFF_PS   = OFF_PL + (size_t)NCHK * NTOK * 4;

  float*          csq  = (float*)(ws + OFF_CSQ);
  float*          tsq  = (float*)(ws + OFF_TSQ);
  int*            cnt  = (int*)(ws + OFF_CNT);
  int*            done = (int*)(ws + OFF_DONE);
  float*          lsum = (float*)(ws + OFF_LSUM);
  int*            list = (int*)(ws + OFF_LIST);
  unsigned char*  Ahs  = (unsigned char*)(ws + OFF_AHS);
  unsigned char*  Atg  = (unsigned char*)(ws + OFF_ATG);
  unsigned char*  Wtb  = (unsigned char*)(ws + OFF_WTB);
  unsigned char*  Cbb  = (unsigned char*)(ws + OFF_CBB);
  float*          pm   = (float*)(ws + OFF_PM);
  float*          pl   = (float*)(ws + OFF_PL);
  float*          ps   = (float*)(ws + OFF_PS);

  hipMemsetAsync(ws, 0, ZERO_BYTES, stream);

  k_prep1<<<1312, 256, 0, stream>>>(ids, cb, W, list, cnt, csq, Wtb, Cbb);
  k_prep_a<<<256, 256, 0, stream>>>(hs, tg, list, cnt, Ahs, Atg, tsq);
  k_dual<<<dim3(64, 64), 256, 0, stream>>>(Atg, Cbb, Ahs, Wtb, csq, bias, cnt,
                                           pm, pl, ps);
  k_merge<<<NTOK / 64, 256, 0, stream>>>(cnt, tsq, pm, pl, ps, lsum, done,
                                         (float*)d_out);
}

// Round 4
// 325.730 us; speedup vs baseline: 2.8389x; 1.0217x over previous
//
#include <hip/hip_runtime.h>
#include <hip/hip_bf16.h>

// ---------------------------------------------------------------------------
// TokenDiscrepancyLoss: loss = 0.1 * sum_{mask} [ (||t||^2 + sum_c p_c (||c||^2 - 2 t.c)) / H ]
// with p = softmax(hs @ W + b) over C=8192.
//
// R10: MX-scaled fp8 32x32x64 k_dual with BK=128 staging. R9 (unroll-1,
// BK=64) was sync-bound: 4 MFMA (~70 cyc) per {vmcnt-wait, 2 barriers} slot,
// 32 slots/tile, MfmaUtil 18.7%. Here each iteration stages a contiguous
// 16 KB (2 slab chunks) per operand (8 loads/wave, vmcnt(8)) and runs
// 8 MFMAs -> 16 slots/tile, 2x work per latency window. acc stays a
// loop-carried phi (#pragma unroll 1) so the R8 operand-tuple spill storm
// cannot recur. LDS 64 KB (2 blocks/CU).
// Dispatches: memset, prep1, prep_a, k_dual, k_merge (5 total).
// ---------------------------------------------------------------------------

#define H        1024
#define CBN      8192
#define NTOK     8192
#define MT       128
#define NTILE    128
#define NKC2     8                // H / 128
#define NCHK     128              // partial strips (one per 64-col wave tile)
#define LOSSW    0.1f
#define CTC      1024.0f          // centering for bf16 ct registers
#define WSCALE   16.0f            // W pre-scale (pow2) for fp8 range
#define SB_UNIT  127              // e8m0 scale = 2^0
#define SB_W     123              // e8m0 scale = 2^-4 (undoes WSCALE)
#define SLAB     131072           // bytes per 128-row panel: 16kc*8KB

typedef __attribute__((ext_vector_type(4)))  int   i32x4;
typedef __attribute__((ext_vector_type(8)))  int   i32x8;
typedef __attribute__((ext_vector_type(16))) float f32x16;

__device__ __forceinline__ unsigned short f2bf(float f) {
  union { float f; unsigned u; } x; x.f = f;
  return (unsigned short)((x.u + 0x7FFFu + ((x.u >> 16) & 1u)) >> 16); // RNE
}
__device__ __forceinline__ float bf2f(unsigned short u) {
  union { unsigned u; float f; } x; x.u = (unsigned)u << 16;
  return x.f;
}

// ---- fp32 -> fp8 e4m3fn (OCP) ----
__device__ unsigned char f2fp8_sw(float f) {
  float a = fabsf(f);
  unsigned s = f < 0.f ? 0x80u : 0u;
  if (!(a < 448.f)) return (unsigned char)(s | 0x7Eu);
  if (a < 0.0009765625f) return (unsigned char)s;
  int e; float m = frexpf(a, &e);
  int te = e - 1;
  if (te < -6) {
    int q = (int)rintf(a * 512.f); if (q > 7) q = 7;
    return (unsigned char)(s | q);
  }
  int q = (int)rintf((2.f * m - 1.f) * 8.f);
  int E = te + 7, M = q;
  if (q == 8) { E += 1; M = 0; }
  if (E > 15) return (unsigned char)(s | 0x7Eu);
  return (unsigned char)(s | (E << 3) | M);
}
__device__ __forceinline__ unsigned pack4(float a, float b, float c, float d) {
#if __has_builtin(__builtin_amdgcn_cvt_pk_fp8_f32)
  int r = __builtin_amdgcn_cvt_pk_fp8_f32(a, b, 0, false);
  r     = __builtin_amdgcn_cvt_pk_fp8_f32(c, d, r, true);
  return (unsigned)r;
#else
  return (unsigned)f2fp8_sw(a) | ((unsigned)f2fp8_sw(b) << 8) |
         ((unsigned)f2fp8_sw(c) << 16) | ((unsigned)f2fp8_sw(d) << 24);
#endif
}

// kc-chunk internal offset for (row c, local k octet g in [0,8)):
//   half = g>>2 (k>>5), b4 = (g>>1)&1 ((k>>4)&1), lo8 = (g&1)*8 (k&8)
//   off  = half*4096 + b4*2048 + c*16 + lo8
__device__ __forceinline__ int slab_off(int g, int c) {
  return ((g >> 2) << 12) + (((g >> 1) & 1) << 11) + (c << 4) + ((g & 1) << 3);
}

// async global->LDS DMA, 16B/lane; LDS dest = wave-uniform base + lane*16
__device__ __forceinline__ void load_lds16(const void* g, void* l) {
  __builtin_amdgcn_global_load_lds((const __attribute__((address_space(1))) void*)g,
                                   (__attribute__((address_space(3))) void*)l,
                                   16, 0, 0);
}
__device__ __forceinline__ void wait_vm8() { asm volatile("s_waitcnt vmcnt(8)" ::: "memory"); }
__device__ __forceinline__ void wait_vm0() { asm volatile("s_waitcnt vmcnt(0)" ::: "memory"); }
__device__ __forceinline__ void barrier_raw() { asm volatile("s_barrier" ::: "memory"); }

// XCD-aware tile mapping
__device__ __forceinline__ void tile_map(int* tilex, int* tiley) {
  const int flat = blockIdx.y * 64 + blockIdx.x;
  const int xcd = flat & 7, loc = flat >> 3;
  *tiley = xcd * 8 + (loc & 7);
  *tilex = loc >> 3;
}

// ---------------- prep1: compact (32 blk) + W (1024 blk) + cb (256 blk) ----
__global__ __launch_bounds__(256) void k_prep1(
    const int* __restrict__ ids, const float* __restrict__ cb,
    const float* __restrict__ W,
    int* __restrict__ list, int* __restrict__ counter,
    float* __restrict__ csq,
    unsigned char* __restrict__ Wtb, unsigned char* __restrict__ Cbb) {
  __shared__ __align__(16) unsigned char tile[8192];
  const int b = blockIdx.x, t = threadIdx.x;
  if (b < 32) {
    int f = 0;
    #pragma unroll
    for (int j = 0; j < 16; ++j) f |= ids[2 * (t * 16 + j) + 1];
    int anyodd = __syncthreads_or(f);
    int i = b * 256 + t;
    int v = anyodd ? ids[i] : ids[2 * i];
    bool act = (v == 1);
    unsigned long long mask = __ballot(act);
    int lane = t & 63;
    int base = 0;
    if (lane == 0) base = atomicAdd(counter, __popcll(mask));
    base = __shfl(base, 0);
    if (act) list[base + __popcll(mask & ((1ull << lane) - 1ull))] = i;
  } else if (b < 1056) {
    // W [H][C] fp32 -> fp8 slab [tiley][kc][half][b4][c][16], scaled x16
    const int q = b - 32, tiley = q >> 4, kc = q & 15;
    const int c = t & 127, gh = t >> 7;
    unsigned char* dst = Wtb + (size_t)tiley * SLAB + (size_t)kc * 8192;
    #pragma unroll
    for (int gi = 0; gi < 4; ++gi) {
      const int g = gh * 4 + gi;
      const float* wp = W + (size_t)(kc * 64 + g * 8) * CBN + tiley * 128 + c;
      float v[8];
      #pragma unroll
      for (int j = 0; j < 8; ++j) v[j] = wp[(size_t)j * CBN] * WSCALE;
      uint2 pk;
      pk.x = pack4(v[0], v[1], v[2], v[3]);
      pk.y = pack4(v[4], v[5], v[6], v[7]);
      *(uint2*)(dst + slab_off(g, c)) = pk;
    }
  } else {
    // codebook [C][H] fp32 -> fp8 slab + csq partials
    const int q = b - 1056, tiley = q >> 2, kcg = q & 3;
    const int r = t >> 1, h = t & 1;
    const int c = tiley * 128 + r;
    float ss = 0.f;
    for (int kk = 0; kk < 4; ++kk) {
      const int kc = kcg * 4 + kk;
      const float4* s4 = (const float4*)(cb + (size_t)c * H + kc * 64 + h * 32);
      #pragma unroll
      for (int i = 0; i < 4; ++i) {
        float4 va = s4[2 * i], vb = s4[2 * i + 1];
        ss += va.x * va.x + va.y * va.y + va.z * va.z + va.w * va.w;
        ss += vb.x * vb.x + vb.y * vb.y + vb.z * vb.z + vb.w * vb.w;
        uint2 pk;
        pk.x = pack4(va.x, va.y, va.z, va.w);
        pk.y = pack4(vb.x, vb.y, vb.z, vb.w);
        *(uint2*)&tile[slab_off(h * 4 + i, r)] = pk;
      }
      __syncthreads();
      const uint4* tp = (const uint4*)tile;
      uint4 x0 = tp[t * 2], x1 = tp[t * 2 + 1];
      unsigned char* dst = Cbb + (size_t)tiley * SLAB + (size_t)kc * 8192 + t * 32;
      *(uint4*)dst = x0; *(uint4*)(dst + 16) = x1;
      __syncthreads();
    }
    ss += __shfl_xor(ss, 1);
    if (h == 0) atomicAdd(&csq[c], ss);
  }
}

// ------- gather active tokens -> fp8 slabs (hs, tg) + fp32 ||t||^2 ---------
__global__ __launch_bounds__(256) void k_prep_a(
    const float* __restrict__ hs, const float* __restrict__ tg,
    const int* __restrict__ list, const int* __restrict__ counter,
    unsigned char* __restrict__ Ahs, unsigned char* __restrict__ Atg,
    float* __restrict__ tsq) {
  const int n = *counter;
  const int n_pad = (n + MT - 1) & ~(MT - 1);
  const int tilex = blockIdx.x >> 2, kcg = blockIdx.x & 3;
  if (tilex * MT >= n_pad) return;
  __shared__ int stok[128];
  __shared__ __align__(16) unsigned char tile[8192];
  const int t = threadIdx.x, r = t >> 1, h = t & 1;
  if (t < 128) {
    int ga = tilex * MT + t;
    stok[t] = list[(ga < n) ? ga : 0];
  }
  __syncthreads();
  const size_t srow = (size_t)stok[r] * H;
  float ss = 0.f;
  for (int kk = 0; kk < 4; ++kk) {
    const int kc = kcg * 4 + kk;
    {
      const float4* s4 = (const float4*)(hs + srow + kc * 64 + h * 32);
      #pragma unroll
      for (int i = 0; i < 4; ++i) {
        float4 va = s4[2 * i], vb = s4[2 * i + 1];
        uint2 pk;
        pk.x = pack4(va.x, va.y, va.z, va.w);
        pk.y = pack4(vb.x, vb.y, vb.z, vb.w);
        *(uint2*)&tile[slab_off(h * 4 + i, r)] = pk;
      }
      __syncthreads();
      const uint4* tp = (const uint4*)tile;
      uint4 x0 = tp[t * 2], x1 = tp[t * 2 + 1];
      unsigned char* dst = Ahs + (size_t)tilex * SLAB + (size_t)kc * 8192 + t * 32;
      *(uint4*)dst = x0; *(uint4*)(dst + 16) = x1;
      __syncthreads();
    }
    {
      const float4* s4 = (const float4*)(tg + srow + kc * 64 + h * 32);
      #pragma unroll
      for (int i = 0; i < 4; ++i) {
        float4 va = s4[2 * i], vb = s4[2 * i + 1];
        ss += va.x * va.x + va.y * va.y + va.z * va.z + va.w * va.w;
        ss += vb.x * vb.x + vb.y * vb.y + vb.z * vb.z + vb.w * vb.w;
        uint2 pk;
        pk.x = pack4(va.x, va.y, va.z, va.w);
        pk.y = pack4(vb.x, vb.y, vb.z, vb.w);
        *(uint2*)&tile[slab_off(h * 4 + i, r)] = pk;
      }
      __syncthreads();
      const uint4* tp = (const uint4*)tile;
      uint4 x0 = tp[t * 2], x1 = tp[t * 2 + 1];
      unsigned char* dst = Atg + (size_t)tilex * SLAB + (size_t)kc * 8192 + t * 32;
      *(uint4*)dst = x0; *(uint4*)(dst + 16) = x1;
      __syncthreads();
    }
  }
  ss += __shfl_xor(ss, 1);
  if (h == 0) atomicAdd(&tsq[tilex * MT + r], ss);
}

// per-wave DMA batch for one BK=128 stage: 16 KB contiguous per operand
// (2 slab chunks); wave w covers rows {w, w+4, w+8, w+12} x 1 KB of each.
// 8 loads/wave total (4 A + 4 B) -> wait vmcnt(8) drains the previous stage.
#define ISSUE2(Aslab, Bslab, kc2, pb)                                       \
  do {                                                                      \
    const unsigned char* ap_ = (Aslab) + Aoff + (size_t)(kc2) * 16384 + lane * 16; \
    const unsigned char* bp_ = (Bslab) + Boff + (size_t)(kc2) * 16384 + lane * 16; \
    _Pragma("unroll")                                                       \
    for (int q_ = 0; q_ < 4; ++q_) {                                        \
      load_lds16(ap_ + (w + 4 * q_) * 1024, &sA[pb][(w + 4 * q_) * 1024]);  \
      load_lds16(bp_ + (w + 4 * q_) * 1024, &sB[pb][(w + 4 * q_) * 1024]);  \
    }                                                                       \
  } while (0)

// one BK=128 compute step: 2 sub-chunks x 4 MX-scaled 32x32x64 fp8 MFMA.
// Per-lane operand: 32 contiguous k-bytes = one MX block:
//   row = lane&31, k = (lane>>5)*32 + [0..31]
// -> two conflict-free stride-16B ds_read_b128 (b4=0 at +0, b4=1 at +2048).
#define COMPUTE_KC2(cur, SB)                                                \
  do {                                                                      \
    _Pragma("unroll")                                                       \
    for (int s_ = 0; s_ < 2; ++s_) {                                        \
      const unsigned char* abase = &sA[cur][s_ * 8192 + rb];                \
      const unsigned char* bbase = &sB[cur][s_ * 8192 + rb];                \
      i32x8 aF[2], bF[2];                                                   \
      _Pragma("unroll")                                                     \
      for (int mi = 0; mi < 2; ++mi) {                                      \
        i32x4 lo = *(const i32x4*)(abase + ((wr * 64 + mi * 32) << 4));     \
        i32x4 hh = *(const i32x4*)(abase + ((wr * 64 + mi * 32) << 4) + 2048); \
        aF[mi] = __builtin_shufflevector(lo, hh, 0, 1, 2, 3, 4, 5, 6, 7);   \
      }                                                                     \
      _Pragma("unroll")                                                     \
      for (int ni = 0; ni < 2; ++ni) {                                      \
        i32x4 lo = *(const i32x4*)(bbase + ((wc * 64 + ni * 32) << 4));     \
        i32x4 hh = *(const i32x4*)(bbase + ((wc * 64 + ni * 32) << 4) + 2048); \
        bF[ni] = __builtin_shufflevector(lo, hh, 0, 1, 2, 3, 4, 5, 6, 7);   \
      }                                                                     \
      _Pragma("unroll")                                                     \
      for (int mi = 0; mi < 2; ++mi)                                        \
        _Pragma("unroll")                                                   \
        for (int ni = 0; ni < 2; ++ni)                                      \
          acc[mi][ni] = __builtin_amdgcn_mfma_scale_f32_32x32x64_f8f6f4(    \
              aF[mi], bF[ni], acc[mi][ni], 0, 0, 0, SB_UNIT, 0, (SB));      \
    }                                                                       \
  } while (0)

// ---------- dual-phase GEMM: cross (ct -> regs) then logits+softmax --------
__global__ __launch_bounds__(256, 2) void k_dual(
    const unsigned char* __restrict__ Atg, const unsigned char* __restrict__ Cbb,
    const unsigned char* __restrict__ Ahs, const unsigned char* __restrict__ Wtb,
    const float* __restrict__ csq, const float* __restrict__ bias,
    const int* __restrict__ counter,
    float* __restrict__ pm, float* __restrict__ pl, float* __restrict__ ps) {
  const int n = *counter;
  int tilex, tiley;
  tile_map(&tilex, &tiley);
  if (tilex * MT >= n) return;

  __shared__ __align__(16) unsigned char sA[2][16384];
  __shared__ __align__(16) unsigned char sB[2][16384];

  const int t = threadIdx.x;
  const int w = t >> 6, lane = t & 63;
  const int wr = w >> 1, wc = w & 1;
  const int hi32 = lane >> 5, lc32 = lane & 31;
  const int rb = (hi32 << 12) + (lc32 << 4);     // half*4096 + row_lane*16
  const size_t Aoff = (size_t)tilex * SLAB;
  const size_t Boff = (size_t)tiley * SLAB;

  const f32x16 fz = {0.f, 0.f, 0.f, 0.f, 0.f, 0.f, 0.f, 0.f,
                     0.f, 0.f, 0.f, 0.f, 0.f, 0.f, 0.f, 0.f};
  f32x16 acc[2][2];
  #pragma unroll
  for (int mi = 0; mi < 2; ++mi)
    #pragma unroll
    for (int ni = 0; ni < 2; ++ni) acc[mi][ni] = fz;

  // ---------------- phase 1: ct = csq - 2 * (tg x codebook^T) --------------
  // #pragma unroll 1: runtime loop keeps acc a loop-carried phi (full unroll
  // spilled 1.4+ GB/dispatch of operand tuples in R7/R8).
  ISSUE2(Atg, Cbb, 0, 0);
  #pragma unroll 1
  for (int kc = 0; kc < NKC2; ++kc) {
    const int cur = kc & 1;
    if (kc + 1 < NKC2) ISSUE2(Atg, Cbb, kc + 1, cur ^ 1);
    else               ISSUE2(Ahs, Wtb, 0, 0);    // phase-boundary prefetch
    wait_vm8();
    barrier_raw();
    COMPUTE_KC2(cur, SB_UNIT);
    barrier_raw();
  }

  // pack ct into bf16-pair registers (no memory round trip)
  unsigned ctp[2][2][8];
  {
    float cqc[2];
    #pragma unroll
    for (int ni = 0; ni < 2; ++ni)
      cqc[ni] = csq[tiley * NTILE + wc * 64 + ni * 32 + lc32] - CTC;
    #pragma unroll
    for (int mi = 0; mi < 2; ++mi)
      #pragma unroll
      for (int ni = 0; ni < 2; ++ni) {
        #pragma unroll
        for (int rp = 0; rp < 8; ++rp) {
          const float v0 = cqc[ni] - 2.f * acc[mi][ni][2 * rp];
          const float v1 = cqc[ni] - 2.f * acc[mi][ni][2 * rp + 1];
          ctp[mi][ni][rp] = (unsigned)f2bf(v0) | ((unsigned)f2bf(v1) << 16);
        }
        acc[mi][ni] = fz;
      }
  }

  // ---------------- phase 2: logits = hs x W^T (W scale folded as 2^-4) ----
  #pragma unroll 1
  for (int kc = 0; kc < NKC2; ++kc) {
    const int cur = kc & 1;
    if (kc + 1 < NKC2) { ISSUE2(Ahs, Wtb, kc + 1, cur ^ 1); wait_vm8(); }
    else               { wait_vm0(); }
    barrier_raw();
    COMPUTE_KC2(cur, SB_W);
    barrier_raw();
  }

  // ---------------- fused softmax epilogue per 64-col strip ----------------
  float bv[2];
  #pragma unroll
  for (int ni = 0; ni < 2; ++ni)
    bv[ni] = bias[tiley * NTILE + wc * 64 + ni * 32 + lc32];

  const int chunk = tiley * 2 + wc;
  #pragma unroll
  for (int mi = 0; mi < 2; ++mi) {
    #pragma unroll
    for (int r = 0; r < 16; ++r) {
      float lg[2], ct[2];
      #pragma unroll
      for (int ni = 0; ni < 2; ++ni) {
        lg[ni] = acc[mi][ni][r] + bv[ni];
        ct[ni] = bf2f((unsigned short)((ctp[mi][ni][r >> 1] >> ((r & 1) * 16)) & 0xFFFFu));
      }
      float tmax = fmaxf(lg[0], lg[1]);
      #pragma unroll
      for (int d = 1; d < 32; d <<= 1) tmax = fmaxf(tmax, __shfl_xor(tmax, d));
      float le = 0.f, se = 0.f;
      #pragma unroll
      for (int ni = 0; ni < 2; ++ni) {
        const float e = __expf(lg[ni] - tmax);
        le += e; se += e * ct[ni];
      }
      #pragma unroll
      for (int d = 1; d < 32; d <<= 1) {
        le += __shfl_xor(le, d);
        se += __shfl_xor(se, d);
      }
      if (lc32 == 0) {
        // 32x32 C/D: row = (r&3) + 8*(r>>2) + 4*(lane>>5), col = lane&31
        const int row = tilex * MT + wr * 64 + mi * 32 + 4 * hi32 + (r & 3) + 8 * (r >> 2);
        pm[chunk * NTOK + row] = tmax;
        pl[chunk * NTOK + row] = le;
        ps[chunk * NTOK + row] = se;
      }
    }
  }
}

// -------- merge strip partials -> scalar loss (last block finalizes) -------
// 128 blocks: 64 tokens x 4 strip-quarters per block; softmax partials
// (M,L,S) merge associatively: M=max Mi; L=sum Li e^{Mi-M}; S likewise.
__global__ __launch_bounds__(256) void k_merge(
    const int* __restrict__ counter, const float* __restrict__ tsq,
    const float* __restrict__ pm, const float* __restrict__ pl,
    const float* __restrict__ ps, float* __restrict__ lsum,
    int* __restrict__ done, float* __restrict__ out) {
  const int n = *counter;
  const int tl = threadIdx.x & 63, jq = threadIdx.x >> 6;
  const int ga = blockIdx.x * 64 + tl;
  float M = -1e30f, L = 0.f, S = 0.f;
  #pragma unroll 4
  for (int j = jq * 32; j < jq * 32 + 32; ++j) M = fmaxf(M, pm[j * NTOK + ga]);
  #pragma unroll 4
  for (int j = jq * 32; j < jq * 32 + 32; ++j) {
    const float e = __expf(pm[j * NTOK + ga] - M);
    L += pl[j * NTOK + ga] * e;
    S += ps[j * NTOK + ga] * e;
  }
  __shared__ float sM[4][64], sL[4][64], sS[4][64];
  sM[jq][tl] = M; sL[jq][tl] = L; sS[jq][tl] = S;
  __syncthreads();
  if (jq == 0) {
    float Mm = fmaxf(fmaxf(sM[0][tl], sM[1][tl]), fmaxf(sM[2][tl], sM[3][tl]));
    float Lt = 0.f, St = 0.f;
    #pragma unroll
    for (int q = 0; q < 4; ++q) {
      const float e = __expf(sM[q][tl] - Mm);
      Lt += sL[q][tl] * e;
      St += sS[q][tl] * e;
    }
    float val = 0.f;
    if (ga < n) val = (tsq[ga] + CTC + St / Lt) * (LOSSW / (float)H);
    #pragma unroll
    for (int d = 1; d < 64; d <<= 1) val += __shfl_xor(val, d);
    if (tl == 0) {
      atomicAdd(lsum, val);
      __threadfence();
      const int tk = atomicAdd(done, 1);
      if (tk == (int)gridDim.x - 1) {
        __threadfence();
        out[0] = atomicAdd(lsum, 0.0f);   // atomic read-back = final sum
      }
    }
  }
}

// ---------------------------------------------------------------------------
extern "C" void kernel_launch(void* const* d_in, const int* in_sizes, int n_in,
                              void* d_out, int out_size, void* d_ws, size_t ws_size,
                              hipStream_t stream) {
  const float* hs   = (const float*)d_in[0];
  const int*   ids  = (const int*)d_in[1];
  const float* tg   = (const float*)d_in[2];
  const float* cb   = (const float*)d_in[3];
  const float* W    = (const float*)d_in[4];
  const float* bias = (const float*)d_in[5];

  char* ws = (char*)d_ws;
  constexpr size_t OFF_CSQ  = 0;                       // f32[8192] (zeroed)
  constexpr size_t OFF_TSQ  = 32768;                   // f32[8192] (zeroed)
  constexpr size_t OFF_CNT  = 65536;                   // int (zeroed)
  constexpr size_t OFF_DONE = 65540;                   // int (zeroed)
  constexpr size_t OFF_LSUM = 65544;                   // f32 (zeroed)
  constexpr size_t ZERO_BYTES = 65548;
  constexpr size_t OFF_LIST = 65664;                   // int[8192]
  constexpr size_t OFF_AHS  = 98432;                   // fp8 slab 8 MiB
  constexpr size_t OFF_ATG  = OFF_AHS + (size_t)NTOK * H;
  constexpr size_t OFF_WTB  = OFF_ATG + (size_t)NTOK * H;
  constexpr size_t OFF_CBB  = OFF_WTB + (size_t)CBN * H;
  constexpr size_t OFF_PM   = OFF_CBB + (size_t)CBN * H;
  constexpr size_t OFF_PL   = OFF_PM + (size_t)NCHK * NTOK * 4;
  constexpr size_t OFF_PS   = OFF_PL + (size_t)NCHK * NTOK * 4;

  float*          csq  = (float*)(ws + OFF_CSQ);
  float*          tsq  = (float*)(ws + OFF_TSQ);
  int*            cnt  = (int*)(ws + OFF_CNT);
  int*            done = (int*)(ws + OFF_DONE);
  float*          lsum = (float*)(ws + OFF_LSUM);
  int*            list = (int*)(ws + OFF_LIST);
  unsigned char*  Ahs  = (unsigned char*)(ws + OFF_AHS);
  unsigned char*  Atg  = (unsigned char*)(ws + OFF_ATG);
  unsigned char*  Wtb  = (unsigned char*)(ws + OFF_WTB);
  unsigned char*  Cbb  = (unsigned char*)(ws + OFF_CBB);
  float*          pm   = (float*)(ws + OFF_PM);
  float*          pl   = (float*)(ws + OFF_PL);
  float*          ps   = (float*)(ws + OFF_PS);

  hipMemsetAsync(ws, 0, ZERO_BYTES, stream);

  k_prep1<<<1312, 256, 0, stream>>>(ids, cb, W, list, cnt, csq, Wtb, Cbb);
  k_prep_a<<<256, 256, 0, stream>>>(hs, tg, list, cnt, Ahs, Atg, tsq);
  k_dual<<<dim3(64, 64), 256, 0, stream>>>(Atg, Cbb, Ahs, Wtb, csq, bias, cnt,
                                           pm, pl, ps);
  k_merge<<<NTOK / 64, 256, 0, stream>>>(cnt, tsq, pm, pl, ps, lsum, done,
                                         (float*)d_out);
}